// Round 1
// 190.365 us; speedup vs baseline: 1.0368x; 1.0368x over previous
//
#include <hip/hip_runtime.h>

// Head attention, B=4 T=4096 C=1024 H=64. f32 in/out, bf16 MFMA compute.
// scores = k @ q^T (reference quirk).
// Counter-backed design rules:
//  - r4..r10: see journal. r11 (this round): proj was latency-bound at 10%
//    occupancy (1 wave/SIMD, 4900 cyc/K-chunk). Fix: 1024 blocks x 16 rows,
//    N split 4x48 across waves, NO LDS/barriers in main loop; Wt pre-swizzled
//    into MFMA B-fragment order so B-loads are contiguous 1KB L2-local reads.

typedef __attribute__((ext_vector_type(8))) short short8;
typedef __attribute__((ext_vector_type(4))) short s16x4;
typedef __attribute__((ext_vector_type(4))) float f32x4;
typedef unsigned short u16;

#define MFMA16(A, B, C) __builtin_amdgcn_mfma_f32_16x16x32_bf16((A), (B), (C), 0, 0, 0)

__device__ __forceinline__ u16 f2b(float f) {
    unsigned int u = __builtin_bit_cast(unsigned int, f);
    u += 0x7fffu + ((u >> 16) & 1u);
    return (u16)(u >> 16);
}
__device__ __forceinline__ float b2f(u16 v) {
    return __builtin_bit_cast(float, (unsigned int)v << 16);
}

// ---------- kernel 1: W -> fragment-ordered WtF, 8 replicas.
// WtF[rep][t][kc][lane][j], t = mat*4 + tl in 0..11, kc in 0..31, lane = quad*16+l16.
// element = bf16( W_mat[ k = kc*32 + quad*8 + j ][ h = tl*16 + l16 ] )
// so a wave's B-fragment load for (tile t, chunk kc) is one contiguous 1KB read.
__global__ __launch_bounds__(256) void wt_kernel(const float* __restrict__ Wk,
                                                 const float* __restrict__ Wq,
                                                 const float* __restrict__ Wv,
                                                 u16* __restrict__ WtF) {
    const int kc = blockIdx.x;       // 0..31
    const int mat = blockIdx.y;      // 0..2
    const float* W = (mat == 0) ? Wk : (mat == 1 ? Wq : Wv);
    const int tid = threadIdx.x;
    const int tl = tid >> 6, lane = tid & 63, quad = lane >> 4, l16 = lane & 15;
    short8 v;
#pragma unroll
    for (int j = 0; j < 8; ++j)
        v[j] = f2b(W[(size_t)(kc * 32 + quad * 8 + j) * 64 + tl * 16 + l16]);
    const size_t dst = ((size_t)((mat * 4 + tl) * 32 + kc) * 64 + lane) * 8;
#pragma unroll
    for (int rep = 0; rep < 8; ++rep)
        *(short8*)(WtF + (size_t)rep * 196608 + dst) = v;
}

// ---------- kernel 2: fused projection. 1024 blocks x 16 rows.
// Wave w computes col-tiles w*3..w*3+2 (48 cols). No LDS in main loop; B read
// directly from fragment-ordered, XCD-local Wt replica. Prefetch depth 1.
__global__ __launch_bounds__(256) void proj_kernel(const float* __restrict__ x,
                                                   const u16* __restrict__ WtF,
                                                   u16* __restrict__ Kb,
                                                   u16* __restrict__ Qb,
                                                   u16* __restrict__ Vt) {
    __shared__ u16 tile[16][200];                    // epilogue bounce only (6.4KB)
    const int tid = threadIdx.x;
    const int w = tid >> 6, lane = tid & 63, quad = lane >> 4, l16 = lane & 15;
    const int mbase = blockIdx.x * 16;
    // replica: block i lands on XCD i%8 -> read the replica resident in that L2
    const u16* Wp = WtF + (size_t)(blockIdx.x & 7) * 196608
                        + (size_t)(w * 3) * 16384 + (size_t)lane * 8;
    const float* xrow = x + (size_t)(mbase + l16) * 1024 + quad * 8;

    f32x4 acc[3];
    acc[0] = (f32x4)(0.0f); acc[1] = (f32x4)(0.0f); acc[2] = (f32x4)(0.0f);

    float4 c0 = *(const float4*)(xrow);
    float4 c1 = *(const float4*)(xrow + 4);
    short8 b0 = *(const short8*)(Wp);
    short8 b1 = *(const short8*)(Wp + 16384);
    short8 b2 = *(const short8*)(Wp + 32768);

#pragma unroll 4
    for (int kc = 0; kc < 32; ++kc) {
        float4 n0, n1;
        short8 p0, p1, p2;
        if (kc < 31) {                               // prefetch next chunk
            n0 = *(const float4*)(xrow + (kc + 1) * 32);
            n1 = *(const float4*)(xrow + (kc + 1) * 32 + 4);
            p0 = *(const short8*)(Wp + (kc + 1) * 512);
            p1 = *(const short8*)(Wp + 16384 + (kc + 1) * 512);
            p2 = *(const short8*)(Wp + 32768 + (kc + 1) * 512);
        }
        short8 a;
        a[0] = f2b(c0.x); a[1] = f2b(c0.y); a[2] = f2b(c0.z); a[3] = f2b(c0.w);
        a[4] = f2b(c1.x); a[5] = f2b(c1.y); a[6] = f2b(c1.z); a[7] = f2b(c1.w);
        acc[0] = MFMA16(a, b0, acc[0]);
        acc[1] = MFMA16(a, b1, acc[1]);
        acc[2] = MFMA16(a, b2, acc[2]);
        if (kc < 31) { c0 = n0; c1 = n1; b0 = p0; b1 = p1; b2 = p2; }
    }

    // epilogue: bounce through LDS, then Kb, 4x Qb replicas, 4x Vt (transposed) replicas
#pragma unroll
    for (int t = 0; t < 3; ++t)
#pragma unroll
        for (int reg = 0; reg < 4; ++reg)
            tile[quad * 4 + reg][(w * 3 + t) * 16 + l16] = f2b(acc[t][reg]);
    __syncthreads();

    const int b = mbase >> 12, t0b = mbase & 4095;
    if (tid < 128) {
        const int row = tid >> 3, cu8 = (tid & 7) * 8;
        short8 v = *(const short8*)&tile[row][cu8];
        *(short8*)(Kb + (size_t)(mbase + row) * 64 + cu8) = v;
    } else {
        const int idx = tid - 128, row = idx >> 3, cu8 = (idx & 7) * 8;
        short8 v = *(const short8*)&tile[row][64 + cu8];
#pragma unroll
        for (int r = 0; r < 4; ++r)
            *(short8*)(Qb + (size_t)r * 1048576 + (size_t)(mbase + row) * 64 + cu8) = v;
    }
    {
        const int h = tid >> 2, q = tid & 3;
        s16x4 v4;
#pragma unroll
        for (int j = 0; j < 4; ++j) v4[j] = tile[q * 4 + j][128 + h];
#pragma unroll
        for (int r = 0; r < 4; ++r)
            *(s16x4*)(Vt + (size_t)r * 1048576 + ((size_t)(b * 64 + h) << 12) + t0b + q * 4) = v4;
    }
}

// ---------- kernel 3: split-S flash attention, max-free softmax, replicated Q/V.
__global__ __launch_bounds__(256) void attn_kernel(const u16* __restrict__ Kb,
                                                   const u16* __restrict__ Qb,
                                                   const u16* __restrict__ Vt,
                                                   u16* __restrict__ Op,
                                                   float* __restrict__ Ml) {
    const int tile = blockIdx.x, chunk = blockIdx.y, b = blockIdx.z;
    if (chunk * 8 > tile) return;
    __shared__ u16 Qs[64 * 64];                      // unpadded: contiguous staging writes
    __shared__ u16 Vs[64 * 64];
    __shared__ u16 Ps[4][16][72];
    const int tid = threadIdx.x;
    const int w = tid >> 6, lane = tid & 63, quad = lane >> 4, l16 = lane & 15;
    const int t0 = tile * 64;
    const int stBeg = chunk * 8;
    const int stEnd = min(chunk * 8 + 7, tile);

    // replica index: simultaneous readers of an s-tile differ in `tile` -> spread x4
    const u16* Qp = Qb + (size_t)(tile & 3) * 1048576;
    const u16* Vp = Vt + (size_t)(tile & 3) * 1048576;

    const int lin0 = tid, lin1 = tid + 256;          // flat staging: dst = lin*8 u16
    const size_t vrow0 = ((size_t)(b * 64 + (lin0 >> 3)) << 12) + (lin0 & 7) * 8;
    const size_t vrow1 = ((size_t)(b * 64 + (lin1 >> 3)) << 12) + (lin1 & 7) * 8;

    short8 aK[2];
#pragma unroll
    for (int kk = 0; kk < 2; ++kk)
        aK[kk] = *(const short8*)(Kb + (size_t)((b << 12) + t0 + w * 16 + l16) * 64 + kk * 32 + quad * 8);

    short8 qr0 = *(const short8*)(Qp + (size_t)((b << 12) + stBeg * 64) * 64 + lin0 * 8);
    short8 qr1 = *(const short8*)(Qp + (size_t)((b << 12) + stBeg * 64) * 64 + lin1 * 8);
    short8 vr0 = *(const short8*)(Vp + vrow0 + stBeg * 64);
    short8 vr1 = *(const short8*)(Vp + vrow1 + stBeg * 64);

    float l_s[4] = {0.0f, 0.0f, 0.0f, 0.0f};
    f32x4 O[4];
#pragma unroll
    for (int nt = 0; nt < 4; ++nt) O[nt] = (f32x4)(0.0f);

    const int trow = w * 16 + quad * 4;
    const int tglob = t0 + trow;

    for (int st = stBeg; st <= stEnd; ++st) {
        const int s0 = st * 64;
        __syncthreads();                              // prev tile's LDS reads done
        *(short8*)(Qs + lin0 * 8) = qr0;
        *(short8*)(Qs + lin1 * 8) = qr1;
        *(short8*)(Vs + lin0 * 8) = vr0;
        *(short8*)(Vs + lin1 * 8) = vr1;
        __syncthreads();
        if (st < stEnd) {                             // next-tile loads fly during compute
            qr0 = *(const short8*)(Qp + (size_t)((b << 12) + (st + 1) * 64) * 64 + lin0 * 8);
            qr1 = *(const short8*)(Qp + (size_t)((b << 12) + (st + 1) * 64) * 64 + lin1 * 8);
            vr0 = *(const short8*)(Vp + vrow0 + (st + 1) * 64);
            vr1 = *(const short8*)(Vp + vrow1 + (st + 1) * 64);
        }

        // S = K @ Q^T
        f32x4 sc[4];
#pragma unroll
        for (int nt = 0; nt < 4; ++nt) sc[nt] = (f32x4)(0.0f);
#pragma unroll
        for (int kk = 0; kk < 2; ++kk)
#pragma unroll
            for (int nt = 0; nt < 4; ++nt) {
                short8 bq = *(const short8*)(Qs + (nt * 16 + l16) * 64 + kk * 32 + quad * 8);
                sc[nt] = MFMA16(aK[kk], bq, sc[nt]);
            }

        // max-free softmax: p = exp(s/8); masked -> exp(-huge) = 0
        float rs[4] = {0.0f, 0.0f, 0.0f, 0.0f};
#pragma unroll
        for (int nt = 0; nt < 4; ++nt) {
            int sg = s0 + nt * 16 + l16;
#pragma unroll
            for (int reg = 0; reg < 4; ++reg) {
                float v = sc[nt][reg] * 0.125f;
                if (st == tile && sg > tglob + reg) v = -1e30f;
                float p = __expf(v);
                rs[reg] += p;
                Ps[w][quad * 4 + reg][nt * 16 + l16] = f2b(p);
            }
        }
#pragma unroll
        for (int reg = 0; reg < 4; ++reg) {
            float v = rs[reg];
            v += __shfl_xor(v, 1);
            v += __shfl_xor(v, 2);
            v += __shfl_xor(v, 4);
            v += __shfl_xor(v, 8);
            l_s[reg] += v;
        }

        // PV (Ps is wave-private; same-wave DS ordering suffices)
#pragma unroll
        for (int kk = 0; kk < 2; ++kk) {
            short8 ap = *(const short8*)&Ps[w][l16][kk * 32 + quad * 8];
#pragma unroll
            for (int nt = 0; nt < 4; ++nt) {
                short8 bv = *(const short8*)(Vs + (nt * 16 + l16) * 64 + kk * 32 + quad * 8);
                O[nt] = MFMA16(ap, bv, O[nt]);
            }
        }
    }

    const int slot = ((b * 64 + tile) * 8 + chunk);
    if (l16 == 0) {
#pragma unroll
        for (int reg = 0; reg < 4; ++reg)
            Ml[(size_t)slot * 64 + trow + reg] = l_s[reg];
    }
#pragma unroll
    for (int nt = 0; nt < 4; ++nt)
#pragma unroll
        for (int reg = 0; reg < 4; ++reg)
            Op[(size_t)slot * 4096 + (size_t)(trow + reg) * 64 + nt * 16 + l16] = f2b(O[nt][reg]);
}

// ---------- kernel 4: combine — plain sums, divide
__global__ __launch_bounds__(256) void combine_kernel(const u16* __restrict__ Op,
                                                      const float* __restrict__ Ml,
                                                      float* __restrict__ out) {
    const int tid = threadIdx.x, cu = tid & 7, r0 = tid >> 3;
    const int tile = blockIdx.x, b = blockIdx.y;
    const int nch = tile / 8 + 1;
    const int slotBase = (b * 64 + tile) * 8;
#pragma unroll
    for (int i = 0; i < 2; ++i) {
        const int row = r0 + 32 * i;
        float L = 0.0f, acc[8];
#pragma unroll
        for (int j = 0; j < 8; ++j) acc[j] = 0.0f;
#pragma unroll
        for (int c = 0; c < 8; ++c) {
            const bool act = c < nch;
            float lraw = Ml[(size_t)(slotBase + c) * 64 + row];
            short8 ov = *(const short8*)(Op + (size_t)(slotBase + c) * 4096 + (size_t)row * 64 + cu * 8);
            L += act ? lraw : 0.0f;
#pragma unroll
            for (int j = 0; j < 8; ++j)
                acc[j] += act ? b2f((u16)ov[j]) : 0.0f;
        }
        float inv = 1.0f / L;
        float* dst = out + ((size_t)(b << 12) + tile * 64 + row) * 64 + cu * 8;
        *(float4*)(dst)     = make_float4(acc[0] * inv, acc[1] * inv, acc[2] * inv, acc[3] * inv);
        *(float4*)(dst + 4) = make_float4(acc[4] * inv, acc[5] * inv, acc[6] * inv, acc[7] * inv);
    }
}

extern "C" void kernel_launch(void* const* d_in, const int* in_sizes, int n_in,
                              void* d_out, int out_size, void* d_ws, size_t ws_size,
                              hipStream_t stream) {
    const float* x  = (const float*)d_in[0];
    const float* Wk = (const float*)d_in[1];
    const float* Wq = (const float*)d_in[2];
    const float* Wv = (const float*)d_in[3];

    u16* ws16 = (u16*)d_ws;
    u16* Wt = ws16;                          // 8 * 196608  = 1,572,864 u16 (3.1 MB)
    u16* Kb = Wt + 1572864;                  // 1,048,576          (2 MB)
    u16* Qb = Kb + 1048576;                  // 4 * 1,048,576      (8 MB, replicas)
    u16* Vt = Qb + 4194304;                  // 4 * 1,048,576      (8 MB, replicas)
    u16* Op = Vt + 4194304;                  // 8,388,608          (16.8 MB)
    float* Ml = (float*)(Op + 8388608);      // 131,072 f32        (0.5 MB)
    // total ws ~38.6 MB

    wt_kernel<<<dim3(32, 3), 256, 0, stream>>>(Wk, Wq, Wv, Wt);
    proj_kernel<<<1024, 256, 0, stream>>>(x, Wt, Kb, Qb, Vt);
    attn_kernel<<<dim3(64, 8, 4), 256, 0, stream>>>(Kb, Qb, Vt, Op, Ml);
    combine_kernel<<<dim3(64, 4), 256, 0, stream>>>(Op, Ml, (float*)d_out);
}

// Round 2
// 163.007 us; speedup vs baseline: 1.2108x; 1.1678x over previous
//
#include <hip/hip_runtime.h>

// Head attention, B=4 T=4096 C=1024 H=64. f32 in/out, bf16 MFMA compute.
// scores = k @ q^T (reference quirk).
// Counter-backed design rules:
//  - r4..r10: see journal. r11: occupancy 10->30% left proj at 63us -> NOT
//    wave-latency-bound. r12 (this round): both slow variants shared divergent
//    x reads (32 lines/instr) + L1-thrashed per-wave B reads. Fix: m97-class
//    GEMM: coalesced global_load_lds staging for x(f32, XOR-swizzled src) and
//    B(fragment-ordered, staged once per block), BM=32, BK=64, 2-phase pipeline.

typedef __attribute__((ext_vector_type(8))) short short8;
typedef __attribute__((ext_vector_type(4))) short s16x4;
typedef __attribute__((ext_vector_type(4))) float f32x4;
typedef unsigned short u16;

#define MFMA16(A, B, C) __builtin_amdgcn_mfma_f32_16x16x32_bf16((A), (B), (C), 0, 0, 0)

__device__ __forceinline__ u16 f2b(float f) {
    unsigned int u = __builtin_bit_cast(unsigned int, f);
    u += 0x7fffu + ((u >> 16) & 1u);
    return (u16)(u >> 16);
}
__device__ __forceinline__ float b2f(u16 v) {
    return __builtin_bit_cast(float, (unsigned int)v << 16);
}

__device__ __forceinline__ void gload16(const void* g, void* l) {
    __builtin_amdgcn_global_load_lds(
        (const __attribute__((address_space(1))) unsigned int*)g,
        (__attribute__((address_space(3))) unsigned int*)l, 16, 0, 0);
}

// ---------- kernel 1: W -> fragment-ordered WtF, 8 replicas.
// WtF[rep][t][kc][lane][j], t = mat*4 + tl in 0..11, kc in 0..31, lane = quad*16+l16.
// element = bf16( W_mat[ k = kc*32 + quad*8 + j ][ h = tl*16 + l16 ] )
__global__ __launch_bounds__(256) void wt_kernel(const float* __restrict__ Wk,
                                                 const float* __restrict__ Wq,
                                                 const float* __restrict__ Wv,
                                                 u16* __restrict__ WtF) {
    const int kc = blockIdx.x;       // 0..31
    const int mat = blockIdx.y;      // 0..2
    const float* W = (mat == 0) ? Wk : (mat == 1 ? Wq : Wv);
    const int tid = threadIdx.x;
    const int tl = tid >> 6, lane = tid & 63, quad = lane >> 4, l16 = lane & 15;
    short8 v;
#pragma unroll
    for (int j = 0; j < 8; ++j)
        v[j] = f2b(W[(size_t)(kc * 32 + quad * 8 + j) * 64 + tl * 16 + l16]);
    const size_t dst = ((size_t)((mat * 4 + tl) * 32 + kc) * 64 + lane) * 8;
#pragma unroll
    for (int rep = 0; rep < 8; ++rep)
        *(short8*)(WtF + (size_t)rep * 196608 + dst) = v;
}

// ---------- kernel 2: fused projection. 512 blocks x 32 rows, N=192 whole.
// LDS: As[2][32][256B] f32 (col-swizzled via source addr), Bs[2][12][2][64][16B] bf16.
// Per wave: 2 row-tiles x 3 col-tiles; BK=64 (2 MFMA k-subchunks). 2-phase pipeline.
__global__ __launch_bounds__(256) void proj_kernel(const float* __restrict__ x,
                                                   const u16* __restrict__ WtF,
                                                   u16* __restrict__ Kb,
                                                   u16* __restrict__ Qb,
                                                   u16* __restrict__ Vt) {
    __shared__ char smem[65536];                     // As: 0..16K (2x8K), Bs: 16K..64K (2x24K)
    const int tid = threadIdx.x;
    const int w = tid >> 6, lane = tid & 63, quad = lane >> 4, l16 = lane & 15;
    const int mbase = blockIdx.x * 32;
    const u16* Wrep = WtF + (size_t)(blockIdx.x & 7) * 196608;  // XCD-local replica
    const char* xblk = (const char*)x + (size_t)mbase * 4096;
    const int wbase16 = (w << 6) * 16;               // wave-uniform LDS unit base (bytes)

    f32x4 acc[2][3];
#pragma unroll
    for (int r = 0; r < 2; ++r)
#pragma unroll
        for (int c = 0; c < 3; ++c) acc[r][c] = (f32x4)(0.0f);

    // stage chunk p into buffer buf: A = 512 units (16B), B = 1536 units (16B)
#define STAGE(buf, p) do {                                                          \
        char* la = smem + (buf) * 8192;                                             \
        char* lb = smem + 16384 + (buf) * 24576;                                    \
        _Pragma("unroll")                                                           \
        for (int i = 0; i < 2; ++i) {                                               \
            int u = i * 256 + tid;                                                  \
            int row = u >> 4;                                                       \
            int cb = ((u & 15) * 16) ^ ((row & 7) << 5);                            \
            gload16(xblk + (size_t)row * 4096 + (size_t)(p) * 256 + cb,             \
                    la + i * 4096 + wbase16);                                       \
        }                                                                           \
        _Pragma("unroll")                                                           \
        for (int i = 0; i < 6; ++i) {                                               \
            int u = i * 256 + tid;                                                  \
            gload16(Wrep + (size_t)(u >> 7) * 16384 + (size_t)(p) * 1024 + (u & 127) * 8, \
                    lb + i * 4096 + wbase16);                                       \
        }                                                                           \
    } while (0)

    STAGE(0, 0);
    __syncthreads();

    for (int t = 0; t < 16; ++t) {
        const int cur = t & 1;
        if (t < 15) STAGE(cur ^ 1, t + 1);           // async prefetch next chunk
        const char* Ab = smem + cur * 8192;
        const char* Bb = smem + 16384 + cur * 24576;
#pragma unroll
        for (int kk = 0; kk < 2; ++kk) {
            short8 af[2];
#pragma unroll
            for (int r = 0; r < 2; ++r) {
                const int row = r * 16 + l16;
                const int c0 = (kk * 128 + quad * 32) ^ ((l16 & 7) << 5);
                f32x4 lo = *(const f32x4*)(Ab + row * 256 + c0);
                f32x4 hi = *(const f32x4*)(Ab + row * 256 + (c0 ^ 16));
                short8 a;
#pragma unroll
                for (int j = 0; j < 4; ++j) {
                    a[j]     = (short)f2b(lo[j]);
                    a[j + 4] = (short)f2b(hi[j]);
                }
                af[r] = a;
            }
#pragma unroll
            for (int c = 0; c < 3; ++c) {
                short8 bf = *(const short8*)(Bb + (((w * 3 + c) * 2 + kk) * 64 + lane) * 16);
                acc[0][c] = MFMA16(af[0], bf, acc[0][c]);
                acc[1][c] = MFMA16(af[1], bf, acc[1][c]);
            }
        }
        __syncthreads();                             // drains vmcnt (stage) + lgkm, swap
    }
#undef STAGE

    // epilogue: bounce through LDS tile[32][200], then Kb, 4x Qb, 4x Vt (transposed)
    u16 (*tile)[200] = (u16(*)[200])smem;
#pragma unroll
    for (int r = 0; r < 2; ++r)
#pragma unroll
        for (int c = 0; c < 3; ++c)
#pragma unroll
            for (int reg = 0; reg < 4; ++reg)
                tile[r * 16 + quad * 4 + reg][(w * 3 + c) * 16 + l16] = f2b(acc[r][c][reg]);
    __syncthreads();

    const int b = mbase >> 12, t0b = mbase & 4095;
    {
        const int row = tid >> 3, cu8 = (tid & 7) * 8;
        short8 vk = *(const short8*)&tile[row][cu8];
        *(short8*)(Kb + (size_t)(mbase + row) * 64 + cu8) = vk;
        short8 vq = *(const short8*)&tile[row][64 + cu8];
#pragma unroll
        for (int r = 0; r < 4; ++r)
            *(short8*)(Qb + (size_t)r * 1048576 + (size_t)(mbase + row) * 64 + cu8) = vq;
    }
    {
        const int h = tid >> 2, toff = (tid & 3) * 8;
        short8 vv;
#pragma unroll
        for (int j = 0; j < 8; ++j) vv[j] = tile[toff + j][128 + h];
#pragma unroll
        for (int r = 0; r < 4; ++r)
            *(short8*)(Vt + (size_t)r * 1048576 + ((size_t)(b * 64 + h) << 12) + t0b + toff) = vv;
    }
}

// ---------- kernel 3: split-S flash attention, max-free softmax, replicated Q/V.
__global__ __launch_bounds__(256) void attn_kernel(const u16* __restrict__ Kb,
                                                   const u16* __restrict__ Qb,
                                                   const u16* __restrict__ Vt,
                                                   u16* __restrict__ Op,
                                                   float* __restrict__ Ml) {
    const int tile = blockIdx.x, chunk = blockIdx.y, b = blockIdx.z;
    if (chunk * 8 > tile) return;
    __shared__ u16 Qs[64 * 64];                      // unpadded: contiguous staging writes
    __shared__ u16 Vs[64 * 64];
    __shared__ u16 Ps[4][16][72];
    const int tid = threadIdx.x;
    const int w = tid >> 6, lane = tid & 63, quad = lane >> 4, l16 = lane & 15;
    const int t0 = tile * 64;
    const int stBeg = chunk * 8;
    const int stEnd = min(chunk * 8 + 7, tile);

    // replica index: simultaneous readers of an s-tile differ in `tile` -> spread x4
    const u16* Qp = Qb + (size_t)(tile & 3) * 1048576;
    const u16* Vp = Vt + (size_t)(tile & 3) * 1048576;

    const int lin0 = tid, lin1 = tid + 256;          // flat staging: dst = lin*8 u16
    const size_t vrow0 = ((size_t)(b * 64 + (lin0 >> 3)) << 12) + (lin0 & 7) * 8;
    const size_t vrow1 = ((size_t)(b * 64 + (lin1 >> 3)) << 12) + (lin1 & 7) * 8;

    short8 aK[2];
#pragma unroll
    for (int kk = 0; kk < 2; ++kk)
        aK[kk] = *(const short8*)(Kb + (size_t)((b << 12) + t0 + w * 16 + l16) * 64 + kk * 32 + quad * 8);

    short8 qr0 = *(const short8*)(Qp + (size_t)((b << 12) + stBeg * 64) * 64 + lin0 * 8);
    short8 qr1 = *(const short8*)(Qp + (size_t)((b << 12) + stBeg * 64) * 64 + lin1 * 8);
    short8 vr0 = *(const short8*)(Vp + vrow0 + stBeg * 64);
    short8 vr1 = *(const short8*)(Vp + vrow1 + stBeg * 64);

    float l_s[4] = {0.0f, 0.0f, 0.0f, 0.0f};
    f32x4 O[4];
#pragma unroll
    for (int nt = 0; nt < 4; ++nt) O[nt] = (f32x4)(0.0f);

    const int trow = w * 16 + quad * 4;
    const int tglob = t0 + trow;

    for (int st = stBeg; st <= stEnd; ++st) {
        const int s0 = st * 64;
        __syncthreads();                              // prev tile's LDS reads done
        *(short8*)(Qs + lin0 * 8) = qr0;
        *(short8*)(Qs + lin1 * 8) = qr1;
        *(short8*)(Vs + lin0 * 8) = vr0;
        *(short8*)(Vs + lin1 * 8) = vr1;
        __syncthreads();
        if (st < stEnd) {                             // next-tile loads fly during compute
            qr0 = *(const short8*)(Qp + (size_t)((b << 12) + (st + 1) * 64) * 64 + lin0 * 8);
            qr1 = *(const short8*)(Qp + (size_t)((b << 12) + (st + 1) * 64) * 64 + lin1 * 8);
            vr0 = *(const short8*)(Vp + vrow0 + (st + 1) * 64);
            vr1 = *(const short8*)(Vp + vrow1 + (st + 1) * 64);
        }

        // S = K @ Q^T
        f32x4 sc[4];
#pragma unroll
        for (int nt = 0; nt < 4; ++nt) sc[nt] = (f32x4)(0.0f);
#pragma unroll
        for (int kk = 0; kk < 2; ++kk)
#pragma unroll
            for (int nt = 0; nt < 4; ++nt) {
                short8 bq = *(const short8*)(Qs + (nt * 16 + l16) * 64 + kk * 32 + quad * 8);
                sc[nt] = MFMA16(aK[kk], bq, sc[nt]);
            }

        // max-free softmax: p = exp(s/8); masked -> exp(-huge) = 0
        float rs[4] = {0.0f, 0.0f, 0.0f, 0.0f};
#pragma unroll
        for (int nt = 0; nt < 4; ++nt) {
            int sg = s0 + nt * 16 + l16;
#pragma unroll
            for (int reg = 0; reg < 4; ++reg) {
                float v = sc[nt][reg] * 0.125f;
                if (st == tile && sg > tglob + reg) v = -1e30f;
                float p = __expf(v);
                rs[reg] += p;
                Ps[w][quad * 4 + reg][nt * 16 + l16] = f2b(p);
            }
        }
#pragma unroll
        for (int reg = 0; reg < 4; ++reg) {
            float v = rs[reg];
            v += __shfl_xor(v, 1);
            v += __shfl_xor(v, 2);
            v += __shfl_xor(v, 4);
            v += __shfl_xor(v, 8);
            l_s[reg] += v;
        }

        // PV (Ps is wave-private; same-wave DS ordering suffices)
#pragma unroll
        for (int kk = 0; kk < 2; ++kk) {
            short8 ap = *(const short8*)&Ps[w][l16][kk * 32 + quad * 8];
#pragma unroll
            for (int nt = 0; nt < 4; ++nt) {
                short8 bv = *(const short8*)(Vs + (nt * 16 + l16) * 64 + kk * 32 + quad * 8);
                O[nt] = MFMA16(ap, bv, O[nt]);
            }
        }
    }

    const int slot = ((b * 64 + tile) * 8 + chunk);
    if (l16 == 0) {
#pragma unroll
        for (int reg = 0; reg < 4; ++reg)
            Ml[(size_t)slot * 64 + trow + reg] = l_s[reg];
    }
#pragma unroll
    for (int nt = 0; nt < 4; ++nt)
#pragma unroll
        for (int reg = 0; reg < 4; ++reg)
            Op[(size_t)slot * 4096 + (size_t)(trow + reg) * 64 + nt * 16 + l16] = f2b(O[nt][reg]);
}

// ---------- kernel 4: combine — plain sums, divide
__global__ __launch_bounds__(256) void combine_kernel(const u16* __restrict__ Op,
                                                      const float* __restrict__ Ml,
                                                      float* __restrict__ out) {
    const int tid = threadIdx.x, cu = tid & 7, r0 = tid >> 3;
    const int tile = blockIdx.x, b = blockIdx.y;
    const int nch = tile / 8 + 1;
    const int slotBase = (b * 64 + tile) * 8;
#pragma unroll
    for (int i = 0; i < 2; ++i) {
        const int row = r0 + 32 * i;
        float L = 0.0f, acc[8];
#pragma unroll
        for (int j = 0; j < 8; ++j) acc[j] = 0.0f;
#pragma unroll
        for (int c = 0; c < 8; ++c) {
            const bool act = c < nch;
            float lraw = Ml[(size_t)(slotBase + c) * 64 + row];
            short8 ov = *(const short8*)(Op + (size_t)(slotBase + c) * 4096 + (size_t)row * 64 + cu * 8);
            L += act ? lraw : 0.0f;
#pragma unroll
            for (int j = 0; j < 8; ++j)
                acc[j] += act ? b2f((u16)ov[j]) : 0.0f;
        }
        float inv = 1.0f / L;
        float* dst = out + ((size_t)(b << 12) + tile * 64 + row) * 64 + cu * 8;
        *(float4*)(dst)     = make_float4(acc[0] * inv, acc[1] * inv, acc[2] * inv, acc[3] * inv);
        *(float4*)(dst + 4) = make_float4(acc[4] * inv, acc[5] * inv, acc[6] * inv, acc[7] * inv);
    }
}

extern "C" void kernel_launch(void* const* d_in, const int* in_sizes, int n_in,
                              void* d_out, int out_size, void* d_ws, size_t ws_size,
                              hipStream_t stream) {
    const float* x  = (const float*)d_in[0];
    const float* Wk = (const float*)d_in[1];
    const float* Wq = (const float*)d_in[2];
    const float* Wv = (const float*)d_in[3];

    u16* ws16 = (u16*)d_ws;
    u16* Wt = ws16;                          // 8 * 196608  = 1,572,864 u16 (3.1 MB)
    u16* Kb = Wt + 1572864;                  // 1,048,576          (2 MB)
    u16* Qb = Kb + 1048576;                  // 4 * 1,048,576      (8 MB, replicas)
    u16* Vt = Qb + 4194304;                  // 4 * 1,048,576      (8 MB, replicas)
    u16* Op = Vt + 4194304;                  // 8,388,608          (16.8 MB)
    float* Ml = (float*)(Op + 8388608);      // 131,072 f32        (0.5 MB)
    // total ws ~38.6 MB

    wt_kernel<<<dim3(32, 3), 256, 0, stream>>>(Wk, Wq, Wv, Wt);
    proj_kernel<<<512, 256, 0, stream>>>(x, Wt, Kb, Qb, Vt);
    attn_kernel<<<dim3(64, 8, 4), 256, 0, stream>>>(Kb, Qb, Vt, Op, Ml);
    combine_kernel<<<dim3(64, 4), 256, 0, stream>>>(Op, Ml, (float*)d_out);
}

// Round 3
// 153.182 us; speedup vs baseline: 1.2884x; 1.0641x over previous
//
#include <hip/hip_runtime.h>

// Head attention, B=4 T=4096 C=1024 H=64. f32 in/out, bf16 MFMA compute.
// scores = k @ q^T (reference quirk).
// Counter-backed design rules:
//  - r4..r12: see journal. r12: proj fixed via coalesced gload_lds staging (63->~12us).
//  - r13 (this round): attn had 6.66M LDS bank-conflict cycles: Qs/Vs rows are 128B,
//    fragment reads put 16 l16-lanes in one 4-bank group (16-way). Fix: XOR swizzle
//    byte ^= ((row&7)<<4) on both store and read sides (m214 analog, +89% there).
//    Also compact grid: pair tile t with 63-t (9 chunks/pair) -> no dead blocks.

typedef __attribute__((ext_vector_type(8))) short short8;
typedef __attribute__((ext_vector_type(4))) short s16x4;
typedef __attribute__((ext_vector_type(4))) float f32x4;
typedef unsigned short u16;

#define MFMA16(A, B, C) __builtin_amdgcn_mfma_f32_16x16x32_bf16((A), (B), (C), 0, 0, 0)

__device__ __forceinline__ u16 f2b(float f) {
    unsigned int u = __builtin_bit_cast(unsigned int, f);
    u += 0x7fffu + ((u >> 16) & 1u);
    return (u16)(u >> 16);
}
__device__ __forceinline__ float b2f(u16 v) {
    return __builtin_bit_cast(float, (unsigned int)v << 16);
}

__device__ __forceinline__ void gload16(const void* g, void* l) {
    __builtin_amdgcn_global_load_lds(
        (const __attribute__((address_space(1))) unsigned int*)g,
        (__attribute__((address_space(3))) unsigned int*)l, 16, 0, 0);
}

// ---------- kernel 1: W -> fragment-ordered WtF, 8 replicas.
// WtF[rep][t][kc][lane][j], t = mat*4 + tl in 0..11, kc in 0..31, lane = quad*16+l16.
// element = bf16( W_mat[ k = kc*32 + quad*8 + j ][ h = tl*16 + l16 ] )
__global__ __launch_bounds__(256) void wt_kernel(const float* __restrict__ Wk,
                                                 const float* __restrict__ Wq,
                                                 const float* __restrict__ Wv,
                                                 u16* __restrict__ WtF) {
    const int kc = blockIdx.x;       // 0..31
    const int mat = blockIdx.y;      // 0..2
    const float* W = (mat == 0) ? Wk : (mat == 1 ? Wq : Wv);
    const int tid = threadIdx.x;
    const int tl = tid >> 6, lane = tid & 63, quad = lane >> 4, l16 = lane & 15;
    short8 v;
#pragma unroll
    for (int j = 0; j < 8; ++j)
        v[j] = f2b(W[(size_t)(kc * 32 + quad * 8 + j) * 64 + tl * 16 + l16]);
    const size_t dst = ((size_t)((mat * 4 + tl) * 32 + kc) * 64 + lane) * 8;
#pragma unroll
    for (int rep = 0; rep < 8; ++rep)
        *(short8*)(WtF + (size_t)rep * 196608 + dst) = v;
}

// ---------- kernel 2: fused projection. 512 blocks x 32 rows, N=192 whole.
// LDS: As[2][32][256B] f32 (col-swizzled via source addr), Bs[2][12][2][64][16B] bf16.
// Per wave: 2 row-tiles x 3 col-tiles; BK=64 (2 MFMA k-subchunks). 2-phase pipeline.
__global__ __launch_bounds__(256) void proj_kernel(const float* __restrict__ x,
                                                   const u16* __restrict__ WtF,
                                                   u16* __restrict__ Kb,
                                                   u16* __restrict__ Qb,
                                                   u16* __restrict__ Vt) {
    __shared__ char smem[65536];                     // As: 0..16K (2x8K), Bs: 16K..64K (2x24K)
    const int tid = threadIdx.x;
    const int w = tid >> 6, lane = tid & 63, quad = lane >> 4, l16 = lane & 15;
    const int mbase = blockIdx.x * 32;
    const u16* Wrep = WtF + (size_t)(blockIdx.x & 7) * 196608;  // XCD-local replica
    const char* xblk = (const char*)x + (size_t)mbase * 4096;
    const int wbase16 = (w << 6) * 16;               // wave-uniform LDS unit base (bytes)

    f32x4 acc[2][3];
#pragma unroll
    for (int r = 0; r < 2; ++r)
#pragma unroll
        for (int c = 0; c < 3; ++c) acc[r][c] = (f32x4)(0.0f);

    // stage chunk p into buffer buf: A = 512 units (16B), B = 1536 units (16B)
#define STAGE(buf, p) do {                                                          \
        char* la = smem + (buf) * 8192;                                             \
        char* lb = smem + 16384 + (buf) * 24576;                                    \
        _Pragma("unroll")                                                           \
        for (int i = 0; i < 2; ++i) {                                               \
            int u = i * 256 + tid;                                                  \
            int row = u >> 4;                                                       \
            int cb = ((u & 15) * 16) ^ ((row & 7) << 5);                            \
            gload16(xblk + (size_t)row * 4096 + (size_t)(p) * 256 + cb,             \
                    la + i * 4096 + wbase16);                                       \
        }                                                                           \
        _Pragma("unroll")                                                           \
        for (int i = 0; i < 6; ++i) {                                               \
            int u = i * 256 + tid;                                                  \
            gload16(Wrep + (size_t)(u >> 7) * 16384 + (size_t)(p) * 1024 + (u & 127) * 8, \
                    lb + i * 4096 + wbase16);                                       \
        }                                                                           \
    } while (0)

    STAGE(0, 0);
    __syncthreads();

    for (int t = 0; t < 16; ++t) {
        const int cur = t & 1;
        if (t < 15) STAGE(cur ^ 1, t + 1);           // async prefetch next chunk
        const char* Ab = smem + cur * 8192;
        const char* Bb = smem + 16384 + cur * 24576;
#pragma unroll
        for (int kk = 0; kk < 2; ++kk) {
            short8 af[2];
#pragma unroll
            for (int r = 0; r < 2; ++r) {
                const int row = r * 16 + l16;
                const int c0 = (kk * 128 + quad * 32) ^ ((l16 & 7) << 5);
                f32x4 lo = *(const f32x4*)(Ab + row * 256 + c0);
                f32x4 hi = *(const f32x4*)(Ab + row * 256 + (c0 ^ 16));
                short8 a;
#pragma unroll
                for (int j = 0; j < 4; ++j) {
                    a[j]     = (short)f2b(lo[j]);
                    a[j + 4] = (short)f2b(hi[j]);
                }
                af[r] = a;
            }
#pragma unroll
            for (int c = 0; c < 3; ++c) {
                short8 bf = *(const short8*)(Bb + (((w * 3 + c) * 2 + kk) * 64 + lane) * 16);
                acc[0][c] = MFMA16(af[0], bf, acc[0][c]);
                acc[1][c] = MFMA16(af[1], bf, acc[1][c]);
            }
        }
        __syncthreads();                             // drains vmcnt (stage) + lgkm, swap
    }
#undef STAGE

    // epilogue: bounce through LDS tile[32][200], then Kb, 4x Qb, 4x Vt (transposed)
    u16 (*tile)[200] = (u16(*)[200])smem;
#pragma unroll
    for (int r = 0; r < 2; ++r)
#pragma unroll
        for (int c = 0; c < 3; ++c)
#pragma unroll
            for (int reg = 0; reg < 4; ++reg)
                tile[r * 16 + quad * 4 + reg][(w * 3 + c) * 16 + l16] = f2b(acc[r][c][reg]);
    __syncthreads();

    const int b = mbase >> 12, t0b = mbase & 4095;
    {
        const int row = tid >> 3, cu8 = (tid & 7) * 8;
        short8 vk = *(const short8*)&tile[row][cu8];
        *(short8*)(Kb + (size_t)(mbase + row) * 64 + cu8) = vk;
        short8 vq = *(const short8*)&tile[row][64 + cu8];
#pragma unroll
        for (int r = 0; r < 4; ++r)
            *(short8*)(Qb + (size_t)r * 1048576 + (size_t)(mbase + row) * 64 + cu8) = vq;
    }
    {
        const int h = tid >> 2, toff = (tid & 3) * 8;
        short8 vv;
#pragma unroll
        for (int j = 0; j < 8; ++j) vv[j] = tile[toff + j][128 + h];
#pragma unroll
        for (int r = 0; r < 4; ++r)
            *(short8*)(Vt + (size_t)r * 1048576 + ((size_t)(b * 64 + h) << 12) + t0b + toff) = vv;
    }
}

// ---------- kernel 3: split-S flash attention, max-free softmax, replicated Q/V.
// Qs/Vs XOR-swizzled (row&7)<<4 on both sides; compacted grid (tile t paired with 63-t).
#define QSWZ(row, cb) ((row) * 128 + ((cb) ^ (((row) & 7) << 4)))
__global__ __launch_bounds__(256) void attn_kernel(const u16* __restrict__ Kb,
                                                   const u16* __restrict__ Qb,
                                                   const u16* __restrict__ Vt,
                                                   u16* __restrict__ Op,
                                                   float* __restrict__ Ml) {
    const int pc = blockIdx.x;                       // 0..287 = pair*9 + c
    const int b = blockIdx.y;
    const int pair = pc / 9, c9 = pc - pair * 9;
    const int nLow = (pair >> 3) + 1;                // chunks(tLow), tLow = pair (0..31)
    const int tile  = (c9 < nLow) ? pair : (63 - pair);
    const int chunk = (c9 < nLow) ? c9 : (c9 - nLow);
    __shared__ u16 Qs[64 * 64];
    __shared__ u16 Vs[64 * 64];
    __shared__ u16 Ps[4][16][72];
    const int tid = threadIdx.x;
    const int w = tid >> 6, lane = tid & 63, quad = lane >> 4, l16 = lane & 15;
    const int t0 = tile * 64;
    const int stBeg = chunk * 8;
    const int stEnd = min(chunk * 8 + 7, tile);

    // replica index: simultaneous readers of an s-tile differ in `tile` -> spread x4
    const u16* Qp = Qb + (size_t)(tile & 3) * 1048576;
    const u16* Vp = Vt + (size_t)(tile & 3) * 1048576;

    const int lin0 = tid, lin1 = tid + 256;
    const int qd0 = QSWZ(lin0 >> 3, (lin0 & 7) * 16);  // swizzled LDS byte offsets
    const int qd1 = QSWZ(lin1 >> 3, (lin1 & 7) * 16);
    const size_t vrow0 = ((size_t)(b * 64 + (lin0 >> 3)) << 12) + (lin0 & 7) * 8;
    const size_t vrow1 = ((size_t)(b * 64 + (lin1 >> 3)) << 12) + (lin1 & 7) * 8;

    short8 aK[2];
#pragma unroll
    for (int kk = 0; kk < 2; ++kk)
        aK[kk] = *(const short8*)(Kb + (size_t)((b << 12) + t0 + w * 16 + l16) * 64 + kk * 32 + quad * 8);

    short8 qr0 = *(const short8*)(Qp + (size_t)((b << 12) + stBeg * 64) * 64 + lin0 * 8);
    short8 qr1 = *(const short8*)(Qp + (size_t)((b << 12) + stBeg * 64) * 64 + lin1 * 8);
    short8 vr0 = *(const short8*)(Vp + vrow0 + stBeg * 64);
    short8 vr1 = *(const short8*)(Vp + vrow1 + stBeg * 64);

    float l_s[4] = {0.0f, 0.0f, 0.0f, 0.0f};
    f32x4 O[4];
#pragma unroll
    for (int nt = 0; nt < 4; ++nt) O[nt] = (f32x4)(0.0f);

    const int trow = w * 16 + quad * 4;
    const int tglob = t0 + trow;

    for (int st = stBeg; st <= stEnd; ++st) {
        const int s0 = st * 64;
        __syncthreads();                              // prev tile's LDS reads done
        *(short8*)((char*)Qs + qd0) = qr0;
        *(short8*)((char*)Qs + qd1) = qr1;
        *(short8*)((char*)Vs + qd0) = vr0;
        *(short8*)((char*)Vs + qd1) = vr1;
        __syncthreads();
        if (st < stEnd) {                             // next-tile loads fly during compute
            qr0 = *(const short8*)(Qp + (size_t)((b << 12) + (st + 1) * 64) * 64 + lin0 * 8);
            qr1 = *(const short8*)(Qp + (size_t)((b << 12) + (st + 1) * 64) * 64 + lin1 * 8);
            vr0 = *(const short8*)(Vp + vrow0 + (st + 1) * 64);
            vr1 = *(const short8*)(Vp + vrow1 + (st + 1) * 64);
        }

        // S = K @ Q^T
        f32x4 sc[4];
#pragma unroll
        for (int nt = 0; nt < 4; ++nt) sc[nt] = (f32x4)(0.0f);
#pragma unroll
        for (int kk = 0; kk < 2; ++kk)
#pragma unroll
            for (int nt = 0; nt < 4; ++nt) {
                short8 bq = *(const short8*)((const char*)Qs + QSWZ(nt * 16 + l16, kk * 64 + quad * 16));
                sc[nt] = MFMA16(aK[kk], bq, sc[nt]);
            }

        // max-free softmax: p = exp(s/8); masked -> exp(-huge) = 0
        float rs[4] = {0.0f, 0.0f, 0.0f, 0.0f};
#pragma unroll
        for (int nt = 0; nt < 4; ++nt) {
            int sg = s0 + nt * 16 + l16;
#pragma unroll
            for (int reg = 0; reg < 4; ++reg) {
                float v = sc[nt][reg] * 0.125f;
                if (st == tile && sg > tglob + reg) v = -1e30f;
                float p = __expf(v);
                rs[reg] += p;
                Ps[w][quad * 4 + reg][nt * 16 + l16] = f2b(p);
            }
        }
#pragma unroll
        for (int reg = 0; reg < 4; ++reg) {
            float v = rs[reg];
            v += __shfl_xor(v, 1);
            v += __shfl_xor(v, 2);
            v += __shfl_xor(v, 4);
            v += __shfl_xor(v, 8);
            l_s[reg] += v;
        }

        // PV (Ps is wave-private; same-wave DS ordering suffices)
#pragma unroll
        for (int kk = 0; kk < 2; ++kk) {
            short8 ap = *(const short8*)&Ps[w][l16][kk * 32 + quad * 8];
#pragma unroll
            for (int nt = 0; nt < 4; ++nt) {
                short8 bv = *(const short8*)((const char*)Vs + QSWZ(nt * 16 + l16, kk * 64 + quad * 16));
                O[nt] = MFMA16(ap, bv, O[nt]);
            }
        }
    }

    const int slot = ((b * 64 + tile) * 8 + chunk);
    if (l16 == 0) {
#pragma unroll
        for (int reg = 0; reg < 4; ++reg)
            Ml[(size_t)slot * 64 + trow + reg] = l_s[reg];
    }
#pragma unroll
    for (int nt = 0; nt < 4; ++nt)
#pragma unroll
        for (int reg = 0; reg < 4; ++reg)
            Op[(size_t)slot * 4096 + (size_t)(trow + reg) * 64 + nt * 16 + l16] = f2b(O[nt][reg]);
}

// ---------- kernel 4: combine — plain sums, divide
__global__ __launch_bounds__(256) void combine_kernel(const u16* __restrict__ Op,
                                                      const float* __restrict__ Ml,
                                                      float* __restrict__ out) {
    const int tid = threadIdx.x, cu = tid & 7, r0 = tid >> 3;
    const int tile = blockIdx.x, b = blockIdx.y;
    const int nch = tile / 8 + 1;
    const int slotBase = (b * 64 + tile) * 8;
#pragma unroll
    for (int i = 0; i < 2; ++i) {
        const int row = r0 + 32 * i;
        float L = 0.0f, acc[8];
#pragma unroll
        for (int j = 0; j < 8; ++j) acc[j] = 0.0f;
#pragma unroll
        for (int c = 0; c < 8; ++c) {
            const bool act = c < nch;
            float lraw = Ml[(size_t)(slotBase + c) * 64 + row];
            short8 ov = *(const short8*)(Op + (size_t)(slotBase + c) * 4096 + (size_t)row * 64 + cu * 8);
            L += act ? lraw : 0.0f;
#pragma unroll
            for (int j = 0; j < 8; ++j)
                acc[j] += act ? b2f((u16)ov[j]) : 0.0f;
        }
        float inv = 1.0f / L;
        float* dst = out + ((size_t)(b << 12) + tile * 64 + row) * 64 + cu * 8;
        *(float4*)(dst)     = make_float4(acc[0] * inv, acc[1] * inv, acc[2] * inv, acc[3] * inv);
        *(float4*)(dst + 4) = make_float4(acc[4] * inv, acc[5] * inv, acc[6] * inv, acc[7] * inv);
    }
}

extern "C" void kernel_launch(void* const* d_in, const int* in_sizes, int n_in,
                              void* d_out, int out_size, void* d_ws, size_t ws_size,
                              hipStream_t stream) {
    const float* x  = (const float*)d_in[0];
    const float* Wk = (const float*)d_in[1];
    const float* Wq = (const float*)d_in[2];
    const float* Wv = (const float*)d_in[3];

    u16* ws16 = (u16*)d_ws;
    u16* Wt = ws16;                          // 8 * 196608  = 1,572,864 u16 (3.1 MB)
    u16* Kb = Wt + 1572864;                  // 1,048,576          (2 MB)
    u16* Qb = Kb + 1048576;                  // 4 * 1,048,576      (8 MB, replicas)
    u16* Vt = Qb + 4194304;                  // 4 * 1,048,576      (8 MB, replicas)
    u16* Op = Vt + 4194304;                  // 8,388,608          (16.8 MB)
    float* Ml = (float*)(Op + 8388608);      // 131,072 f32        (0.5 MB)
    // total ws ~38.6 MB

    wt_kernel<<<dim3(32, 3), 256, 0, stream>>>(Wk, Wq, Wv, Wt);
    proj_kernel<<<512, 256, 0, stream>>>(x, Wt, Kb, Qb, Vt);
    attn_kernel<<<dim3(288, 4), 256, 0, stream>>>(Kb, Qb, Vt, Op, Ml);
    combine_kernel<<<dim3(64, 4), 256, 0, stream>>>(Op, Ml, (float*)d_out);
}

// Round 6
// 151.204 us; speedup vs baseline: 1.3053x; 1.0131x over previous
//
#include <hip/hip_runtime.h>

// Head attention, B=4 T=4096 C=1024 H=64. f32 in/out, bf16 MFMA compute.
// scores = k @ q^T (reference quirk).
// Counter-backed design rules:
//  - r4..r13: see journal. r13: Qs/Vs XOR swizzle + compact grid (attn 52.7->~35).
//  - r14: ds_read_b64_tr_b16 Ps path FAILED correctness (mapping ambiguous) -> reverted.
//  - r15: keep r3 Ps[16][72] round-trip; keep the two verified-safe wins:
//    (a) defer row-sum shfl reduce to epilogue (sums commute; -16 ds_swizzle/step),
//    (c) native __bf16 cast (1 VALU op) + exp2f with folded scale.
//  - r16 (this round): r15 never ran (container infra failure) -> resubmit unchanged.

typedef __attribute__((ext_vector_type(8))) short short8;
typedef __attribute__((ext_vector_type(4))) short s16x4;
typedef __attribute__((ext_vector_type(4))) float f32x4;
typedef unsigned short u16;

#define MFMA16(A, B, C) __builtin_amdgcn_mfma_f32_16x16x32_bf16((A), (B), (C), 0, 0, 0)

__device__ __forceinline__ u16 f2b(float f) {
    __bf16 h = (__bf16)f;                     // RNE hw convert; backend pk-fuses pairs
    return __builtin_bit_cast(u16, h);
}
__device__ __forceinline__ float b2f(u16 v) {
    return __builtin_bit_cast(float, (unsigned int)v << 16);
}

__device__ __forceinline__ void gload16(const void* g, void* l) {
    __builtin_amdgcn_global_load_lds(
        (const __attribute__((address_space(1))) unsigned int*)g,
        (__attribute__((address_space(3))) unsigned int*)l, 16, 0, 0);
}

// ---------- kernel 1: W -> fragment-ordered WtF, 8 replicas.
// WtF[rep][t][kc][lane][j], t = mat*4 + tl in 0..11, kc in 0..31, lane = quad*16+l16.
// element = bf16( W_mat[ k = kc*32 + quad*8 + j ][ h = tl*16 + l16 ] )
__global__ __launch_bounds__(256) void wt_kernel(const float* __restrict__ Wk,
                                                 const float* __restrict__ Wq,
                                                 const float* __restrict__ Wv,
                                                 u16* __restrict__ WtF) {
    const int kc = blockIdx.x;       // 0..31
    const int mat = blockIdx.y;      // 0..2
    const float* W = (mat == 0) ? Wk : (mat == 1 ? Wq : Wv);
    const int tid = threadIdx.x;
    const int tl = tid >> 6, lane = tid & 63, quad = lane >> 4, l16 = lane & 15;
    short8 v;
#pragma unroll
    for (int j = 0; j < 8; ++j)
        v[j] = f2b(W[(size_t)(kc * 32 + quad * 8 + j) * 64 + tl * 16 + l16]);
    const size_t dst = ((size_t)((mat * 4 + tl) * 32 + kc) * 64 + lane) * 8;
#pragma unroll
    for (int rep = 0; rep < 8; ++rep)
        *(short8*)(WtF + (size_t)rep * 196608 + dst) = v;
}

// ---------- kernel 2: fused projection. 512 blocks x 32 rows, N=192 whole.
// LDS: As[2][32][256B] f32 (col-swizzled via source addr), Bs[2][12][2][64][16B] bf16.
// Per wave: 2 row-tiles x 3 col-tiles; BK=64 (2 MFMA k-subchunks). 2-phase pipeline.
__global__ __launch_bounds__(256) void proj_kernel(const float* __restrict__ x,
                                                   const u16* __restrict__ WtF,
                                                   u16* __restrict__ Kb,
                                                   u16* __restrict__ Qb,
                                                   u16* __restrict__ Vt) {
    __shared__ char smem[65536];                     // As: 0..16K (2x8K), Bs: 16K..64K (2x24K)
    const int tid = threadIdx.x;
    const int w = tid >> 6, lane = tid & 63, quad = lane >> 4, l16 = lane & 15;
    const int mbase = blockIdx.x * 32;
    const u16* Wrep = WtF + (size_t)(blockIdx.x & 7) * 196608;  // XCD-local replica
    const char* xblk = (const char*)x + (size_t)mbase * 4096;
    const int wbase16 = (w << 6) * 16;               // wave-uniform LDS unit base (bytes)

    f32x4 acc[2][3];
#pragma unroll
    for (int r = 0; r < 2; ++r)
#pragma unroll
        for (int c = 0; c < 3; ++c) acc[r][c] = (f32x4)(0.0f);

    // stage chunk p into buffer buf: A = 512 units (16B), B = 1536 units (16B)
#define STAGE(buf, p) do {                                                          \
        char* la = smem + (buf) * 8192;                                             \
        char* lb = smem + 16384 + (buf) * 24576;                                    \
        _Pragma("unroll")                                                           \
        for (int i = 0; i < 2; ++i) {                                               \
            int u = i * 256 + tid;                                                  \
            int row = u >> 4;                                                       \
            int cb = ((u & 15) * 16) ^ ((row & 7) << 5);                            \
            gload16(xblk + (size_t)row * 4096 + (size_t)(p) * 256 + cb,             \
                    la + i * 4096 + wbase16);                                       \
        }                                                                           \
        _Pragma("unroll")                                                           \
        for (int i = 0; i < 6; ++i) {                                               \
            int u = i * 256 + tid;                                                  \
            gload16(Wrep + (size_t)(u >> 7) * 16384 + (size_t)(p) * 1024 + (u & 127) * 8, \
                    lb + i * 4096 + wbase16);                                       \
        }                                                                           \
    } while (0)

    STAGE(0, 0);
    __syncthreads();

    for (int t = 0; t < 16; ++t) {
        const int cur = t & 1;
        if (t < 15) STAGE(cur ^ 1, t + 1);           // async prefetch next chunk
        const char* Ab = smem + cur * 8192;
        const char* Bb = smem + 16384 + cur * 24576;
#pragma unroll
        for (int kk = 0; kk < 2; ++kk) {
            short8 af[2];
#pragma unroll
            for (int r = 0; r < 2; ++r) {
                const int row = r * 16 + l16;
                const int c0 = (kk * 128 + quad * 32) ^ ((l16 & 7) << 5);
                f32x4 lo = *(const f32x4*)(Ab + row * 256 + c0);
                f32x4 hi = *(const f32x4*)(Ab + row * 256 + (c0 ^ 16));
                short8 a;
#pragma unroll
                for (int j = 0; j < 4; ++j) {
                    a[j]     = (short)f2b(lo[j]);
                    a[j + 4] = (short)f2b(hi[j]);
                }
                af[r] = a;
            }
#pragma unroll
            for (int c = 0; c < 3; ++c) {
                short8 bf = *(const short8*)(Bb + (((w * 3 + c) * 2 + kk) * 64 + lane) * 16);
                acc[0][c] = MFMA16(af[0], bf, acc[0][c]);
                acc[1][c] = MFMA16(af[1], bf, acc[1][c]);
            }
        }
        __syncthreads();                             // drains vmcnt (stage) + lgkm, swap
    }
#undef STAGE

    // epilogue: bounce through LDS tile[32][200], then Kb, 4x Qb, 4x Vt (transposed)
    u16 (*tile)[200] = (u16(*)[200])smem;
#pragma unroll
    for (int r = 0; r < 2; ++r)
#pragma unroll
        for (int c = 0; c < 3; ++c)
#pragma unroll
            for (int reg = 0; reg < 4; ++reg)
                tile[r * 16 + quad * 4 + reg][(w * 3 + c) * 16 + l16] = f2b(acc[r][c][reg]);
    __syncthreads();

    const int b = mbase >> 12, t0b = mbase & 4095;
    {
        const int row = tid >> 3, cu8 = (tid & 7) * 8;
        short8 vk = *(const short8*)&tile[row][cu8];
        *(short8*)(Kb + (size_t)(mbase + row) * 64 + cu8) = vk;
        short8 vq = *(const short8*)&tile[row][64 + cu8];
#pragma unroll
        for (int r = 0; r < 4; ++r)
            *(short8*)(Qb + (size_t)r * 1048576 + (size_t)(mbase + row) * 64 + cu8) = vq;
    }
    {
        const int h = tid >> 2, toff = (tid & 3) * 8;
        short8 vv;
#pragma unroll
        for (int j = 0; j < 8; ++j) vv[j] = tile[toff + j][128 + h];
#pragma unroll
        for (int r = 0; r < 4; ++r)
            *(short8*)(Vt + (size_t)r * 1048576 + ((size_t)(b * 64 + h) << 12) + t0b + toff) = vv;
    }
}

// ---------- kernel 3: split-S flash attention, max-free softmax, replicated Q/V.
// Qs/Vs XOR-swizzled; Ps[16][72] LDS round-trip (r3-verified); deferred l-reduce.
#define QSWZ(row, cb) ((row) * 128 + ((cb) ^ (((row) & 7) << 4)))
__global__ __launch_bounds__(256) void attn_kernel(const u16* __restrict__ Kb,
                                                   const u16* __restrict__ Qb,
                                                   const u16* __restrict__ Vt,
                                                   u16* __restrict__ Op,
                                                   float* __restrict__ Ml) {
    const int pc = blockIdx.x;                       // 0..287 = pair*9 + c
    const int b = blockIdx.y;
    const int pair = pc / 9, c9 = pc - pair * 9;
    const int nLow = (pair >> 3) + 1;                // chunks(tLow), tLow = pair (0..31)
    const int tile  = (c9 < nLow) ? pair : (63 - pair);
    const int chunk = (c9 < nLow) ? c9 : (c9 - nLow);
    __shared__ u16 Qs[64 * 64];
    __shared__ u16 Vs[64 * 64];
    __shared__ u16 Ps[4][16][72];
    const int tid = threadIdx.x;
    const int w = tid >> 6, lane = tid & 63, quad = lane >> 4, l16 = lane & 15;
    const int t0 = tile * 64;
    const int stBeg = chunk * 8;
    const int stEnd = min(chunk * 8 + 7, tile);

    // replica index: simultaneous readers of an s-tile differ in `tile` -> spread x4
    const u16* Qp = Qb + (size_t)(tile & 3) * 1048576;
    const u16* Vp = Vt + (size_t)(tile & 3) * 1048576;

    const int lin0 = tid, lin1 = tid + 256;
    const int qd0 = QSWZ(lin0 >> 3, (lin0 & 7) * 16);  // swizzled LDS byte offsets
    const int qd1 = QSWZ(lin1 >> 3, (lin1 & 7) * 16);
    const size_t vrow0 = ((size_t)(b * 64 + (lin0 >> 3)) << 12) + (lin0 & 7) * 8;
    const size_t vrow1 = ((size_t)(b * 64 + (lin1 >> 3)) << 12) + (lin1 & 7) * 8;

    short8 aK[2];
#pragma unroll
    for (int kk = 0; kk < 2; ++kk)
        aK[kk] = *(const short8*)(Kb + (size_t)((b << 12) + t0 + w * 16 + l16) * 64 + kk * 32 + quad * 8);

    short8 qr0 = *(const short8*)(Qp + (size_t)((b << 12) + stBeg * 64) * 64 + lin0 * 8);
    short8 qr1 = *(const short8*)(Qp + (size_t)((b << 12) + stBeg * 64) * 64 + lin1 * 8);
    short8 vr0 = *(const short8*)(Vp + vrow0 + stBeg * 64);
    short8 vr1 = *(const short8*)(Vp + vrow1 + stBeg * 64);

    float l_acc[4] = {0.0f, 0.0f, 0.0f, 0.0f};       // deferred: reduce over l16 at end
    f32x4 O[4];
#pragma unroll
    for (int nt = 0; nt < 4; ++nt) O[nt] = (f32x4)(0.0f);

    const int trow = w * 16 + quad * 4;
    const int tglob = t0 + trow;

    for (int st = stBeg; st <= stEnd; ++st) {
        const int s0 = st * 64;
        __syncthreads();                              // prev tile's LDS reads done
        *(short8*)((char*)Qs + qd0) = qr0;
        *(short8*)((char*)Qs + qd1) = qr1;
        *(short8*)((char*)Vs + qd0) = vr0;
        *(short8*)((char*)Vs + qd1) = vr1;
        __syncthreads();
        if (st < stEnd) {                             // next-tile loads fly during compute
            qr0 = *(const short8*)(Qp + (size_t)((b << 12) + (st + 1) * 64) * 64 + lin0 * 8);
            qr1 = *(const short8*)(Qp + (size_t)((b << 12) + (st + 1) * 64) * 64 + lin1 * 8);
            vr0 = *(const short8*)(Vp + vrow0 + (st + 1) * 64);
            vr1 = *(const short8*)(Vp + vrow1 + (st + 1) * 64);
        }

        // S = K @ Q^T
        f32x4 sc[4];
#pragma unroll
        for (int nt = 0; nt < 4; ++nt) sc[nt] = (f32x4)(0.0f);
#pragma unroll
        for (int kk = 0; kk < 2; ++kk)
#pragma unroll
            for (int nt = 0; nt < 4; ++nt) {
                short8 bq = *(const short8*)((const char*)Qs + QSWZ(nt * 16 + l16, kk * 64 + quad * 16));
                sc[nt] = MFMA16(aK[kk], bq, sc[nt]);
            }

        // max-free softmax: p = exp2(s * 0.125*log2e); masked -> 0. No per-step reduce.
#pragma unroll
        for (int nt = 0; nt < 4; ++nt) {
            int sg = s0 + nt * 16 + l16;
#pragma unroll
            for (int reg = 0; reg < 4; ++reg) {
                float v = sc[nt][reg];
                if (st == tile && sg > tglob + reg) v = -1e30f;
                float p = exp2f(v * 0.18033688011112042f);   // exp(v/8)
                l_acc[reg] += p;
                Ps[w][quad * 4 + reg][nt * 16 + l16] = f2b(p);
            }
        }

        // PV (Ps is wave-private; same-wave DS ordering suffices)
#pragma unroll
        for (int kk = 0; kk < 2; ++kk) {
            short8 ap = *(const short8*)&Ps[w][l16][kk * 32 + quad * 8];
#pragma unroll
            for (int nt = 0; nt < 4; ++nt) {
                short8 bv = *(const short8*)((const char*)Vs + QSWZ(nt * 16 + l16, kk * 64 + quad * 16));
                O[nt] = MFMA16(ap, bv, O[nt]);
            }
        }
    }

    const int slot = ((b * 64 + tile) * 8 + chunk);
    {   // deferred row-sum reduction (once per block, not per step)
#pragma unroll
        for (int reg = 0; reg < 4; ++reg) {
            float v = l_acc[reg];
            v += __shfl_xor(v, 1);
            v += __shfl_xor(v, 2);
            v += __shfl_xor(v, 4);
            v += __shfl_xor(v, 8);
            if (l16 == 0) Ml[(size_t)slot * 64 + trow + reg] = v;
        }
    }
#pragma unroll
    for (int nt = 0; nt < 4; ++nt)
#pragma unroll
        for (int reg = 0; reg < 4; ++reg)
            Op[(size_t)slot * 4096 + (size_t)(trow + reg) * 64 + nt * 16 + l16] = f2b(O[nt][reg]);
}

// ---------- kernel 4: combine — plain sums, divide
__global__ __launch_bounds__(256) void combine_kernel(const u16* __restrict__ Op,
                                                      const float* __restrict__ Ml,
                                                      float* __restrict__ out) {
    const int tid = threadIdx.x, cu = tid & 7, r0 = tid >> 3;
    const int tile = blockIdx.x, b = blockIdx.y;
    const int nch = tile / 8 + 1;
    const int slotBase = (b * 64 + tile) * 8;
#pragma unroll
    for (int i = 0; i < 2; ++i) {
        const int row = r0 + 32 * i;
        float L = 0.0f, acc[8];
#pragma unroll
        for (int j = 0; j < 8; ++j) acc[j] = 0.0f;
#pragma unroll
        for (int c = 0; c < 8; ++c) {
            const bool act = c < nch;
            float lraw = Ml[(size_t)(slotBase + c) * 64 + row];
            short8 ov = *(const short8*)(Op + (size_t)(slotBase + c) * 4096 + (size_t)row * 64 + cu * 8);
            L += act ? lraw : 0.0f;
#pragma unroll
            for (int j = 0; j < 8; ++j)
                acc[j] += act ? b2f((u16)ov[j]) : 0.0f;
        }
        float inv = 1.0f / L;
        float* dst = out + ((size_t)(b << 12) + tile * 64 + row) * 64 + cu * 8;
        *(float4*)(dst)     = make_float4(acc[0] * inv, acc[1] * inv, acc[2] * inv, acc[3] * inv);
        *(float4*)(dst + 4) = make_float4(acc[4] * inv, acc[5] * inv, acc[6] * inv, acc[7] * inv);
    }
}

extern "C" void kernel_launch(void* const* d_in, const int* in_sizes, int n_in,
                              void* d_out, int out_size, void* d_ws, size_t ws_size,
                              hipStream_t stream) {
    const float* x  = (const float*)d_in[0];
    const float* Wk = (const float*)d_in[1];
    const float* Wq = (const float*)d_in[2];
    const float* Wv = (const float*)d_in[3];

    u16* ws16 = (u16*)d_ws;
    u16* Wt = ws16;                          // 8 * 196608  = 1,572,864 u16 (3.1 MB)
    u16* Kb = Wt + 1572864;                  // 1,048,576          (2 MB)
    u16* Qb = Kb + 1048576;                  // 4 * 1,048,576      (8 MB, replicas)
    u16* Vt = Qb + 4194304;                  // 4 * 1,048,576      (8 MB, replicas)
    u16* Op = Vt + 4194304;                  // 8,388,608          (16.8 MB)
    float* Ml = (float*)(Op + 8388608);      // 131,072 f32        (0.5 MB)
    // total ws ~38.6 MB

    wt_kernel<<<dim3(32, 3), 256, 0, stream>>>(Wk, Wq, Wv, Wt);
    proj_kernel<<<512, 256, 0, stream>>>(x, Wt, Kb, Qb, Vt);
    attn_kernel<<<dim3(288, 4), 256, 0, stream>>>(Kb, Qb, Vt, Op, Ml);
    combine_kernel<<<dim3(64, 4), 256, 0, stream>>>(Op, Ml, (float*)d_out);
}

// Round 7
// 148.956 us; speedup vs baseline: 1.3250x; 1.0151x over previous
//
#include <hip/hip_runtime.h>

// Head attention, B=4 T=4096 C=1024 H=64. f32 in/out, bf16 MFMA compute.
// scores = k @ q^T (reference quirk).
// Counter-backed design rules:
//  - r4..r15: see journal. r13: Qs/Vs XOR swizzle + compact grid. r15: deferred
//    l-reduce + native bf16 cast (153->151).
//  - r17 (this round): amortize attn per-step overhead: KVBLK=128 (half the
//    barriers/staging per unit work), swapped QK (mfma(Q,K): same aK data, C-frag
//    s-consecutive per reg) -> Ps packed ds_write_b64 + ds_read_b128 at bank floor
//    (stride 272B), l_acc scalar. DS ops/128-step 76->52, barriers 4->2.

typedef __attribute__((ext_vector_type(8))) short short8;
typedef __attribute__((ext_vector_type(4))) short s16x4;
typedef __attribute__((ext_vector_type(4))) float f32x4;
typedef unsigned short u16;

#define MFMA16(A, B, C) __builtin_amdgcn_mfma_f32_16x16x32_bf16((A), (B), (C), 0, 0, 0)

__device__ __forceinline__ u16 f2b(float f) {
    __bf16 h = (__bf16)f;                     // RNE hw convert; backend pk-fuses pairs
    return __builtin_bit_cast(u16, h);
}
__device__ __forceinline__ float b2f(u16 v) {
    return __builtin_bit_cast(float, (unsigned int)v << 16);
}

__device__ __forceinline__ void gload16(const void* g, void* l) {
    __builtin_amdgcn_global_load_lds(
        (const __attribute__((address_space(1))) unsigned int*)g,
        (__attribute__((address_space(3))) unsigned int*)l, 16, 0, 0);
}

// ---------- kernel 1: W -> fragment-ordered WtF, 8 replicas.
// WtF[rep][t][kc][lane][j], t = mat*4 + tl in 0..11, kc in 0..31, lane = quad*16+l16.
// element = bf16( W_mat[ k = kc*32 + quad*8 + j ][ h = tl*16 + l16 ] )
__global__ __launch_bounds__(256) void wt_kernel(const float* __restrict__ Wk,
                                                 const float* __restrict__ Wq,
                                                 const float* __restrict__ Wv,
                                                 u16* __restrict__ WtF) {
    const int kc = blockIdx.x;       // 0..31
    const int mat = blockIdx.y;      // 0..2
    const float* W = (mat == 0) ? Wk : (mat == 1 ? Wq : Wv);
    const int tid = threadIdx.x;
    const int tl = tid >> 6, lane = tid & 63, quad = lane >> 4, l16 = lane & 15;
    short8 v;
#pragma unroll
    for (int j = 0; j < 8; ++j)
        v[j] = f2b(W[(size_t)(kc * 32 + quad * 8 + j) * 64 + tl * 16 + l16]);
    const size_t dst = ((size_t)((mat * 4 + tl) * 32 + kc) * 64 + lane) * 8;
#pragma unroll
    for (int rep = 0; rep < 8; ++rep)
        *(short8*)(WtF + (size_t)rep * 196608 + dst) = v;
}

// ---------- kernel 2: fused projection. 512 blocks x 32 rows, N=192 whole.
// LDS: As[2][32][256B] f32 (col-swizzled via source addr), Bs[2][12][2][64][16B] bf16.
// Per wave: 2 row-tiles x 3 col-tiles; BK=64 (2 MFMA k-subchunks). 2-phase pipeline.
__global__ __launch_bounds__(256) void proj_kernel(const float* __restrict__ x,
                                                   const u16* __restrict__ WtF,
                                                   u16* __restrict__ Kb,
                                                   u16* __restrict__ Qb,
                                                   u16* __restrict__ Vt) {
    __shared__ char smem[65536];                     // As: 0..16K (2x8K), Bs: 16K..64K (2x24K)
    const int tid = threadIdx.x;
    const int w = tid >> 6, lane = tid & 63, quad = lane >> 4, l16 = lane & 15;
    const int mbase = blockIdx.x * 32;
    const u16* Wrep = WtF + (size_t)(blockIdx.x & 7) * 196608;  // XCD-local replica
    const char* xblk = (const char*)x + (size_t)mbase * 4096;
    const int wbase16 = (w << 6) * 16;               // wave-uniform LDS unit base (bytes)

    f32x4 acc[2][3];
#pragma unroll
    for (int r = 0; r < 2; ++r)
#pragma unroll
        for (int c = 0; c < 3; ++c) acc[r][c] = (f32x4)(0.0f);

    // stage chunk p into buffer buf: A = 512 units (16B), B = 1536 units (16B)
#define STAGE(buf, p) do {                                                          \
        char* la = smem + (buf) * 8192;                                             \
        char* lb = smem + 16384 + (buf) * 24576;                                    \
        _Pragma("unroll")                                                           \
        for (int i = 0; i < 2; ++i) {                                               \
            int u = i * 256 + tid;                                                  \
            int row = u >> 4;                                                       \
            int cb = ((u & 15) * 16) ^ ((row & 7) << 5);                            \
            gload16(xblk + (size_t)row * 4096 + (size_t)(p) * 256 + cb,             \
                    la + i * 4096 + wbase16);                                       \
        }                                                                           \
        _Pragma("unroll")                                                           \
        for (int i = 0; i < 6; ++i) {                                               \
            int u = i * 256 + tid;                                                  \
            gload16(Wrep + (size_t)(u >> 7) * 16384 + (size_t)(p) * 1024 + (u & 127) * 8, \
                    lb + i * 4096 + wbase16);                                       \
        }                                                                           \
    } while (0)

    STAGE(0, 0);
    __syncthreads();

    for (int t = 0; t < 16; ++t) {
        const int cur = t & 1;
        if (t < 15) STAGE(cur ^ 1, t + 1);           // async prefetch next chunk
        const char* Ab = smem + cur * 8192;
        const char* Bb = smem + 16384 + cur * 24576;
#pragma unroll
        for (int kk = 0; kk < 2; ++kk) {
            short8 af[2];
#pragma unroll
            for (int r = 0; r < 2; ++r) {
                const int row = r * 16 + l16;
                const int c0 = (kk * 128 + quad * 32) ^ ((l16 & 7) << 5);
                f32x4 lo = *(const f32x4*)(Ab + row * 256 + c0);
                f32x4 hi = *(const f32x4*)(Ab + row * 256 + (c0 ^ 16));
                short8 a;
#pragma unroll
                for (int j = 0; j < 4; ++j) {
                    a[j]     = (short)f2b(lo[j]);
                    a[j + 4] = (short)f2b(hi[j]);
                }
                af[r] = a;
            }
#pragma unroll
            for (int c = 0; c < 3; ++c) {
                short8 bf = *(const short8*)(Bb + (((w * 3 + c) * 2 + kk) * 64 + lane) * 16);
                acc[0][c] = MFMA16(af[0], bf, acc[0][c]);
                acc[1][c] = MFMA16(af[1], bf, acc[1][c]);
            }
        }
        __syncthreads();                             // drains vmcnt (stage) + lgkm, swap
    }
#undef STAGE

    // epilogue: bounce through LDS tile[32][200], then Kb, 4x Qb, 4x Vt (transposed)
    u16 (*tile)[200] = (u16(*)[200])smem;
#pragma unroll
    for (int r = 0; r < 2; ++r)
#pragma unroll
        for (int c = 0; c < 3; ++c)
#pragma unroll
            for (int reg = 0; reg < 4; ++reg)
                tile[r * 16 + quad * 4 + reg][(w * 3 + c) * 16 + l16] = f2b(acc[r][c][reg]);
    __syncthreads();

    const int b = mbase >> 12, t0b = mbase & 4095;
    {
        const int row = tid >> 3, cu8 = (tid & 7) * 8;
        short8 vk = *(const short8*)&tile[row][cu8];
        *(short8*)(Kb + (size_t)(mbase + row) * 64 + cu8) = vk;
        short8 vq = *(const short8*)&tile[row][64 + cu8];
#pragma unroll
        for (int r = 0; r < 4; ++r)
            *(short8*)(Qb + (size_t)r * 1048576 + (size_t)(mbase + row) * 64 + cu8) = vq;
    }
    {
        const int h = tid >> 2, toff = (tid & 3) * 8;
        short8 vv;
#pragma unroll
        for (int j = 0; j < 8; ++j) vv[j] = tile[toff + j][128 + h];
#pragma unroll
        for (int r = 0; r < 4; ++r)
            *(short8*)(Vt + (size_t)r * 1048576 + ((size_t)(b * 64 + h) << 12) + t0b + toff) = vv;
    }
}

// ---------- kernel 3: split-S flash attention, KVBLK=128, swapped QK, packed Ps.
// Qs[128 s][64 h] swz (row&7)<<4; Vs[64 h][128 s] swz (row&15)<<4;
// Ps per wave [16 t][128 s] u16, row stride 272B (write b64 / read b128 at bank floor).
#define QSWZ(row, cb) ((row) * 128 + ((cb) ^ (((row) & 7) << 4)))
#define VSWZ(row, cb) ((row) * 256 + ((cb) ^ (((row) & 15) << 4)))
__global__ __launch_bounds__(256) void attn_kernel(const u16* __restrict__ Kb,
                                                   const u16* __restrict__ Qb,
                                                   const u16* __restrict__ Vt,
                                                   u16* __restrict__ Op,
                                                   float* __restrict__ Ml) {
    const int pc = blockIdx.x;                       // 0..287 = pair*9 + c
    const int b = blockIdx.y;
    const int pair = pc / 9, c9 = pc - pair * 9;
    const int nLow = (pair >> 3) + 1;                // chunks(tLow), tLow = pair (0..31)
    const int tile  = (c9 < nLow) ? pair : (63 - pair);
    const int chunk = (c9 < nLow) ? c9 : (c9 - nLow);
    __shared__ char smem[50176];                     // Qs 16K | Vs 16K | Ps 4x4352
    u16* Qs = (u16*)smem;
    u16* Vs = (u16*)(smem + 16384);
    const int tid = threadIdx.x;
    const int w = tid >> 6, lane = tid & 63, quad = lane >> 4, l16 = lane & 15;
    char* psB = smem + 32768 + w * 4352;             // wave-private P
    const int t0 = tile * 64;
    const int bsBeg = chunk * 4;                     // 128-wide s blocks
    const int bsEnd = min(chunk * 4 + 3, tile >> 1);
    const int bsDiag = tile >> 1;

    // replica index: simultaneous readers of an s-tile differ in `tile` -> spread x4
    const u16* Qp = Qb + (size_t)(tile & 3) * 1048576;
    const u16* Vp = Vt + (size_t)(tile & 3) * 1048576;

    // staging addresses: 1024 16B-units; Q: row=lin>>3 (128), V: row h=lin>>4 (64)
    int qd[4], vd[4];
    size_t qg[4], vg[4];
#pragma unroll
    for (int i = 0; i < 4; ++i) {
        const int lin = tid + i * 256;
        qd[i] = QSWZ(lin >> 3, (lin & 7) * 16);
        vd[i] = VSWZ(lin >> 4, (lin & 15) * 16);
        qg[i] = ((size_t)(b << 12) + (lin >> 3)) * 64 + (lin & 7) * 8;
        vg[i] = ((size_t)(b * 64 + (lin >> 4)) << 12) + (lin & 15) * 8;
    }

    short8 aK[2];
#pragma unroll
    for (int kk = 0; kk < 2; ++kk)
        aK[kk] = *(const short8*)(Kb + (size_t)((b << 12) + t0 + w * 16 + l16) * 64 + kk * 32 + quad * 8);

    short8 qr[4], vr[4];
#pragma unroll
    for (int i = 0; i < 4; ++i) {
        qr[i] = *(const short8*)(Qp + qg[i] + (size_t)bsBeg * 8192);
        vr[i] = *(const short8*)(Vp + vg[i] + bsBeg * 128);
    }

    float l_acc = 0.0f;                              // lane's t-row = w*16+l16
    f32x4 O[4];
#pragma unroll
    for (int ht = 0; ht < 4; ++ht) O[ht] = (f32x4)(0.0f);

    const int tg = t0 + w * 16 + l16;

    for (int bs = bsBeg; bs <= bsEnd; ++bs) {
        __syncthreads();                              // prev tile's LDS reads done
#pragma unroll
        for (int i = 0; i < 4; ++i) {
            *(short8*)(smem + qd[i]) = qr[i];
            *(short8*)(smem + 16384 + vd[i]) = vr[i];
        }
        __syncthreads();
        if (bs < bsEnd) {                             // next-tile loads fly during compute
#pragma unroll
            for (int i = 0; i < 4; ++i) {
                qr[i] = *(const short8*)(Qp + qg[i] + (size_t)(bs + 1) * 8192);
                vr[i] = *(const short8*)(Vp + vg[i] + (bs + 1) * 128);
            }
        }

        // S^T tile via swapped operands: C[m=s=nt*16+quad*4+reg][n=t=l16]
        f32x4 sc[8];
#pragma unroll
        for (int nt = 0; nt < 8; ++nt) sc[nt] = (f32x4)(0.0f);
#pragma unroll
        for (int kk = 0; kk < 2; ++kk)
#pragma unroll
            for (int nt = 0; nt < 8; ++nt) {
                short8 aq = *(const short8*)(smem + QSWZ(nt * 16 + l16, kk * 64 + quad * 16));
                sc[nt] = MFMA16(aq, aK[kk], sc[nt]);
            }

        // max-free softmax; P[t=l16][s] packed: 4 s-consecutive regs -> one b64 write
#pragma unroll
        for (int nt = 0; nt < 8; ++nt) {
            const int sgBase = bs * 128 + nt * 16 + quad * 4;
            s16x4 v4;
#pragma unroll
            for (int reg = 0; reg < 4; ++reg) {
                float v = sc[nt][reg];
                if (bs == bsDiag && sgBase + reg > tg) v = -1e30f;
                float p = exp2f(v * 0.18033688011112042f);   // exp(v/8)
                l_acc += p;
                v4[reg] = (short)f2b(p);
            }
            *(s16x4*)(psB + l16 * 272 + nt * 32 + quad * 8) = v4;
        }

        // PV: A = P (m=t=l16, k=s), B = V (n=h). Ps is wave-private.
#pragma unroll
        for (int kk = 0; kk < 4; ++kk) {
            short8 ap = *(const short8*)(psB + l16 * 272 + kk * 64 + quad * 16);
#pragma unroll
            for (int ht = 0; ht < 4; ++ht) {
                short8 bv = *(const short8*)(smem + 16384 + VSWZ(ht * 16 + l16, kk * 64 + quad * 16));
                O[ht] = MFMA16(ap, bv, O[ht]);
            }
        }
    }

    const int slot = ((b * 64 + tile) * 8 + chunk);
    {   // deferred row-sum: reduce over the 4 quads (lanes differing in bits 4-5)
        float v = l_acc;
        v += __shfl_xor(v, 16);
        v += __shfl_xor(v, 32);
        if (quad == 0) Ml[(size_t)slot * 64 + w * 16 + l16] = v;
    }
    const int trow = w * 16 + quad * 4;
#pragma unroll
    for (int ht = 0; ht < 4; ++ht)
#pragma unroll
        for (int reg = 0; reg < 4; ++reg)
            Op[(size_t)slot * 4096 + (size_t)(trow + reg) * 64 + ht * 16 + l16] = f2b(O[ht][reg]);
}

// ---------- kernel 4: combine — plain sums, divide
__global__ __launch_bounds__(256) void combine_kernel(const u16* __restrict__ Op,
                                                      const float* __restrict__ Ml,
                                                      float* __restrict__ out) {
    const int tid = threadIdx.x, cu = tid & 7, r0 = tid >> 3;
    const int tile = blockIdx.x, b = blockIdx.y;
    const int nch = tile / 8 + 1;
    const int slotBase = (b * 64 + tile) * 8;
#pragma unroll
    for (int i = 0; i < 2; ++i) {
        const int row = r0 + 32 * i;
        float L = 0.0f, acc[8];
#pragma unroll
        for (int j = 0; j < 8; ++j) acc[j] = 0.0f;
#pragma unroll
        for (int c = 0; c < 8; ++c) {
            const bool act = c < nch;
            float lraw = Ml[(size_t)(slotBase + c) * 64 + row];
            short8 ov = *(const short8*)(Op + (size_t)(slotBase + c) * 4096 + (size_t)row * 64 + cu * 8);
            L += act ? lraw : 0.0f;
#pragma unroll
            for (int j = 0; j < 8; ++j)
                acc[j] += act ? b2f((u16)ov[j]) : 0.0f;
        }
        float inv = 1.0f / L;
        float* dst = out + ((size_t)(b << 12) + tile * 64 + row) * 64 + cu * 8;
        *(float4*)(dst)     = make_float4(acc[0] * inv, acc[1] * inv, acc[2] * inv, acc[3] * inv);
        *(float4*)(dst + 4) = make_float4(acc[4] * inv, acc[5] * inv, acc[6] * inv, acc[7] * inv);
    }
}

extern "C" void kernel_launch(void* const* d_in, const int* in_sizes, int n_in,
                              void* d_out, int out_size, void* d_ws, size_t ws_size,
                              hipStream_t stream) {
    const float* x  = (const float*)d_in[0];
    const float* Wk = (const float*)d_in[1];
    const float* Wq = (const float*)d_in[2];
    const float* Wv = (const float*)d_in[3];

    u16* ws16 = (u16*)d_ws;
    u16* Wt = ws16;                          // 8 * 196608  = 1,572,864 u16 (3.1 MB)
    u16* Kb = Wt + 1572864;                  // 1,048,576          (2 MB)
    u16* Qb = Kb + 1048576;                  // 4 * 1,048,576      (8 MB, replicas)
    u16* Vt = Qb + 4194304;                  // 4 * 1,048,576      (8 MB, replicas)
    u16* Op = Vt + 4194304;                  // 8,388,608          (16.8 MB)
    float* Ml = (float*)(Op + 8388608);      // 131,072 f32        (0.5 MB)
    // total ws ~38.6 MB

    wt_kernel<<<dim3(32, 3), 256, 0, stream>>>(Wk, Wq, Wv, Wt);
    proj_kernel<<<512, 256, 0, stream>>>(x, Wt, Kb, Qb, Vt);
    attn_kernel<<<dim3(288, 4), 256, 0, stream>>>(Kb, Qb, Vt, Op, Ml);
    combine_kernel<<<dim3(64, 4), 256, 0, stream>>>(Op, Ml, (float*)d_out);
}

// Round 8
// 147.101 us; speedup vs baseline: 1.3417x; 1.0126x over previous
//
#include <hip/hip_runtime.h>

// Head attention, B=4 T=4096 C=1024 H=64. f32 in/out, bf16 MFMA compute.
// scores = k @ q^T (reference quirk).
// Counter-backed design rules:
//  - r4..r17: see journal. r17: KVBLK=128 + swapped QK + packed Ps (151->149).
//  - r18 (this round): attn grid was 1152 blocks at 768 co-resident (3/CU) ->
//    1.5 dispatch rounds, half-empty tail. Chunk width 512->1024: pair(t,63-t)
//    = exactly 5 blocks -> grid 640 <= 768, single balanced round. Also halves
//    Op/Ml round-trip (16.8->8.4 MB) and combine reads.

typedef __attribute__((ext_vector_type(8))) short short8;
typedef __attribute__((ext_vector_type(4))) short s16x4;
typedef __attribute__((ext_vector_type(4))) float f32x4;
typedef unsigned short u16;

#define MFMA16(A, B, C) __builtin_amdgcn_mfma_f32_16x16x32_bf16((A), (B), (C), 0, 0, 0)

__device__ __forceinline__ u16 f2b(float f) {
    __bf16 h = (__bf16)f;                     // RNE hw convert; backend pk-fuses pairs
    return __builtin_bit_cast(u16, h);
}
__device__ __forceinline__ float b2f(u16 v) {
    return __builtin_bit_cast(float, (unsigned int)v << 16);
}

__device__ __forceinline__ void gload16(const void* g, void* l) {
    __builtin_amdgcn_global_load_lds(
        (const __attribute__((address_space(1))) unsigned int*)g,
        (__attribute__((address_space(3))) unsigned int*)l, 16, 0, 0);
}

// ---------- kernel 1: W -> fragment-ordered WtF, 8 replicas.
// WtF[rep][t][kc][lane][j], t = mat*4 + tl in 0..11, kc in 0..31, lane = quad*16+l16.
// element = bf16( W_mat[ k = kc*32 + quad*8 + j ][ h = tl*16 + l16 ] )
__global__ __launch_bounds__(256) void wt_kernel(const float* __restrict__ Wk,
                                                 const float* __restrict__ Wq,
                                                 const float* __restrict__ Wv,
                                                 u16* __restrict__ WtF) {
    const int kc = blockIdx.x;       // 0..31
    const int mat = blockIdx.y;      // 0..2
    const float* W = (mat == 0) ? Wk : (mat == 1 ? Wq : Wv);
    const int tid = threadIdx.x;
    const int tl = tid >> 6, lane = tid & 63, quad = lane >> 4, l16 = lane & 15;
    short8 v;
#pragma unroll
    for (int j = 0; j < 8; ++j)
        v[j] = f2b(W[(size_t)(kc * 32 + quad * 8 + j) * 64 + tl * 16 + l16]);
    const size_t dst = ((size_t)((mat * 4 + tl) * 32 + kc) * 64 + lane) * 8;
#pragma unroll
    for (int rep = 0; rep < 8; ++rep)
        *(short8*)(WtF + (size_t)rep * 196608 + dst) = v;
}

// ---------- kernel 2: fused projection. 512 blocks x 32 rows, N=192 whole.
// LDS: As[2][32][256B] f32 (col-swizzled via source addr), Bs[2][12][2][64][16B] bf16.
// Per wave: 2 row-tiles x 3 col-tiles; BK=64 (2 MFMA k-subchunks). 2-phase pipeline.
__global__ __launch_bounds__(256) void proj_kernel(const float* __restrict__ x,
                                                   const u16* __restrict__ WtF,
                                                   u16* __restrict__ Kb,
                                                   u16* __restrict__ Qb,
                                                   u16* __restrict__ Vt) {
    __shared__ char smem[65536];                     // As: 0..16K (2x8K), Bs: 16K..64K (2x24K)
    const int tid = threadIdx.x;
    const int w = tid >> 6, lane = tid & 63, quad = lane >> 4, l16 = lane & 15;
    const int mbase = blockIdx.x * 32;
    const u16* Wrep = WtF + (size_t)(blockIdx.x & 7) * 196608;  // XCD-local replica
    const char* xblk = (const char*)x + (size_t)mbase * 4096;
    const int wbase16 = (w << 6) * 16;               // wave-uniform LDS unit base (bytes)

    f32x4 acc[2][3];
#pragma unroll
    for (int r = 0; r < 2; ++r)
#pragma unroll
        for (int c = 0; c < 3; ++c) acc[r][c] = (f32x4)(0.0f);

    // stage chunk p into buffer buf: A = 512 units (16B), B = 1536 units (16B)
#define STAGE(buf, p) do {                                                          \
        char* la = smem + (buf) * 8192;                                             \
        char* lb = smem + 16384 + (buf) * 24576;                                    \
        _Pragma("unroll")                                                           \
        for (int i = 0; i < 2; ++i) {                                               \
            int u = i * 256 + tid;                                                  \
            int row = u >> 4;                                                       \
            int cb = ((u & 15) * 16) ^ ((row & 7) << 5);                            \
            gload16(xblk + (size_t)row * 4096 + (size_t)(p) * 256 + cb,             \
                    la + i * 4096 + wbase16);                                       \
        }                                                                           \
        _Pragma("unroll")                                                           \
        for (int i = 0; i < 6; ++i) {                                               \
            int u = i * 256 + tid;                                                  \
            gload16(Wrep + (size_t)(u >> 7) * 16384 + (size_t)(p) * 1024 + (u & 127) * 8, \
                    lb + i * 4096 + wbase16);                                       \
        }                                                                           \
    } while (0)

    STAGE(0, 0);
    __syncthreads();

    for (int t = 0; t < 16; ++t) {
        const int cur = t & 1;
        if (t < 15) STAGE(cur ^ 1, t + 1);           // async prefetch next chunk
        const char* Ab = smem + cur * 8192;
        const char* Bb = smem + 16384 + cur * 24576;
#pragma unroll
        for (int kk = 0; kk < 2; ++kk) {
            short8 af[2];
#pragma unroll
            for (int r = 0; r < 2; ++r) {
                const int row = r * 16 + l16;
                const int c0 = (kk * 128 + quad * 32) ^ ((l16 & 7) << 5);
                f32x4 lo = *(const f32x4*)(Ab + row * 256 + c0);
                f32x4 hi = *(const f32x4*)(Ab + row * 256 + (c0 ^ 16));
                short8 a;
#pragma unroll
                for (int j = 0; j < 4; ++j) {
                    a[j]     = (short)f2b(lo[j]);
                    a[j + 4] = (short)f2b(hi[j]);
                }
                af[r] = a;
            }
#pragma unroll
            for (int c = 0; c < 3; ++c) {
                short8 bf = *(const short8*)(Bb + (((w * 3 + c) * 2 + kk) * 64 + lane) * 16);
                acc[0][c] = MFMA16(af[0], bf, acc[0][c]);
                acc[1][c] = MFMA16(af[1], bf, acc[1][c]);
            }
        }
        __syncthreads();                             // drains vmcnt (stage) + lgkm, swap
    }
#undef STAGE

    // epilogue: bounce through LDS tile[32][200], then Kb, 4x Qb, 4x Vt (transposed)
    u16 (*tile)[200] = (u16(*)[200])smem;
#pragma unroll
    for (int r = 0; r < 2; ++r)
#pragma unroll
        for (int c = 0; c < 3; ++c)
#pragma unroll
            for (int reg = 0; reg < 4; ++reg)
                tile[r * 16 + quad * 4 + reg][(w * 3 + c) * 16 + l16] = f2b(acc[r][c][reg]);
    __syncthreads();

    const int b = mbase >> 12, t0b = mbase & 4095;
    {
        const int row = tid >> 3, cu8 = (tid & 7) * 8;
        short8 vk = *(const short8*)&tile[row][cu8];
        *(short8*)(Kb + (size_t)(mbase + row) * 64 + cu8) = vk;
        short8 vq = *(const short8*)&tile[row][64 + cu8];
#pragma unroll
        for (int r = 0; r < 4; ++r)
            *(short8*)(Qb + (size_t)r * 1048576 + (size_t)(mbase + row) * 64 + cu8) = vq;
    }
    {
        const int h = tid >> 2, toff = (tid & 3) * 8;
        short8 vv;
#pragma unroll
        for (int j = 0; j < 8; ++j) vv[j] = tile[toff + j][128 + h];
#pragma unroll
        for (int r = 0; r < 4; ++r)
            *(short8*)(Vt + (size_t)r * 1048576 + ((size_t)(b * 64 + h) << 12) + t0b + toff) = vv;
    }
}

// ---------- kernel 3: split-S flash attention, KVBLK=128, swapped QK, packed Ps.
// Chunk width 1024 (8 big-steps); pair(t,63-t) = 5 blocks -> 640-block single round.
#define QSWZ(row, cb) ((row) * 128 + ((cb) ^ (((row) & 7) << 4)))
#define VSWZ(row, cb) ((row) * 256 + ((cb) ^ (((row) & 15) << 4)))
__global__ __launch_bounds__(256) void attn_kernel(const u16* __restrict__ Kb,
                                                   const u16* __restrict__ Qb,
                                                   const u16* __restrict__ Vt,
                                                   u16* __restrict__ Op,
                                                   float* __restrict__ Ml) {
    const int pc = blockIdx.x;                       // 0..159 = pair*5 + c
    const int b = blockIdx.y;
    const int pair = pc / 5, c5 = pc - pair * 5;
    const int nLow = (pair >> 4) + 1;                // chunks(tLow), tLow = pair (0..31)
    const int tile  = (c5 < nLow) ? pair : (63 - pair);
    const int chunk = (c5 < nLow) ? c5 : (c5 - nLow);
    __shared__ char smem[50176];                     // Qs 16K | Vs 16K | Ps 4x4352
    const int tid = threadIdx.x;
    const int w = tid >> 6, lane = tid & 63, quad = lane >> 4, l16 = lane & 15;
    char* psB = smem + 32768 + w * 4352;             // wave-private P
    const int t0 = tile * 64;
    const int bsBeg = chunk * 8;                     // 128-wide s blocks
    const int bsEnd = min(chunk * 8 + 7, tile >> 1);
    const int bsDiag = tile >> 1;

    // replica index: simultaneous readers of an s-tile differ in `tile` -> spread x4
    const u16* Qp = Qb + (size_t)(tile & 3) * 1048576;
    const u16* Vp = Vt + (size_t)(tile & 3) * 1048576;

    // staging addresses: 1024 16B-units; Q: row=lin>>3 (128), V: row h=lin>>4 (64)
    int qd[4], vd[4];
    size_t qg[4], vg[4];
#pragma unroll
    for (int i = 0; i < 4; ++i) {
        const int lin = tid + i * 256;
        qd[i] = QSWZ(lin >> 3, (lin & 7) * 16);
        vd[i] = VSWZ(lin >> 4, (lin & 15) * 16);
        qg[i] = ((size_t)(b << 12) + (lin >> 3)) * 64 + (lin & 7) * 8;
        vg[i] = ((size_t)(b * 64 + (lin >> 4)) << 12) + (lin & 15) * 8;
    }

    short8 aK[2];
#pragma unroll
    for (int kk = 0; kk < 2; ++kk)
        aK[kk] = *(const short8*)(Kb + (size_t)((b << 12) + t0 + w * 16 + l16) * 64 + kk * 32 + quad * 8);

    short8 qr[4], vr[4];
#pragma unroll
    for (int i = 0; i < 4; ++i) {
        qr[i] = *(const short8*)(Qp + qg[i] + (size_t)bsBeg * 8192);
        vr[i] = *(const short8*)(Vp + vg[i] + bsBeg * 128);
    }

    float l_acc = 0.0f;                              // lane's t-row = w*16+l16
    f32x4 O[4];
#pragma unroll
    for (int ht = 0; ht < 4; ++ht) O[ht] = (f32x4)(0.0f);

    const int tg = t0 + w * 16 + l16;

    for (int bs = bsBeg; bs <= bsEnd; ++bs) {
        __syncthreads();                              // prev tile's LDS reads done
#pragma unroll
        for (int i = 0; i < 4; ++i) {
            *(short8*)(smem + qd[i]) = qr[i];
            *(short8*)(smem + 16384 + vd[i]) = vr[i];
        }
        __syncthreads();
        if (bs < bsEnd) {                             // next-tile loads fly during compute
#pragma unroll
            for (int i = 0; i < 4; ++i) {
                qr[i] = *(const short8*)(Qp + qg[i] + (size_t)(bs + 1) * 8192);
                vr[i] = *(const short8*)(Vp + vg[i] + (bs + 1) * 128);
            }
        }

        // S^T tile via swapped operands: C[m=s=nt*16+quad*4+reg][n=t=l16]
        f32x4 sc[8];
#pragma unroll
        for (int nt = 0; nt < 8; ++nt) sc[nt] = (f32x4)(0.0f);
#pragma unroll
        for (int kk = 0; kk < 2; ++kk)
#pragma unroll
            for (int nt = 0; nt < 8; ++nt) {
                short8 aq = *(const short8*)(smem + QSWZ(nt * 16 + l16, kk * 64 + quad * 16));
                sc[nt] = MFMA16(aq, aK[kk], sc[nt]);
            }

        // max-free softmax; P[t=l16][s] packed: 4 s-consecutive regs -> one b64 write
#pragma unroll
        for (int nt = 0; nt < 8; ++nt) {
            const int sgBase = bs * 128 + nt * 16 + quad * 4;
            s16x4 v4;
#pragma unroll
            for (int reg = 0; reg < 4; ++reg) {
                float v = sc[nt][reg];
                if (bs == bsDiag && sgBase + reg > tg) v = -1e30f;
                float p = exp2f(v * 0.18033688011112042f);   // exp(v/8)
                l_acc += p;
                v4[reg] = (short)f2b(p);
            }
            *(s16x4*)(psB + l16 * 272 + nt * 32 + quad * 8) = v4;
        }

        // PV: A = P (m=t=l16, k=s), B = V (n=h). Ps is wave-private.
#pragma unroll
        for (int kk = 0; kk < 4; ++kk) {
            short8 ap = *(const short8*)(psB + l16 * 272 + kk * 64 + quad * 16);
#pragma unroll
            for (int ht = 0; ht < 4; ++ht) {
                short8 bv = *(const short8*)(smem + 16384 + VSWZ(ht * 16 + l16, kk * 64 + quad * 16));
                O[ht] = MFMA16(ap, bv, O[ht]);
            }
        }
    }

    const int slot = ((b * 64 + tile) * 4 + chunk);
    {   // deferred row-sum: reduce over the 4 quads (lanes differing in bits 4-5)
        float v = l_acc;
        v += __shfl_xor(v, 16);
        v += __shfl_xor(v, 32);
        if (quad == 0) Ml[(size_t)slot * 64 + w * 16 + l16] = v;
    }
    const int trow = w * 16 + quad * 4;
#pragma unroll
    for (int ht = 0; ht < 4; ++ht)
#pragma unroll
        for (int reg = 0; reg < 4; ++reg)
            Op[(size_t)slot * 4096 + (size_t)(trow + reg) * 64 + ht * 16 + l16] = f2b(O[ht][reg]);
}

// ---------- kernel 4: combine — plain sums over 4 chunk slots, divide
__global__ __launch_bounds__(256) void combine_kernel(const u16* __restrict__ Op,
                                                      const float* __restrict__ Ml,
                                                      float* __restrict__ out) {
    const int tid = threadIdx.x, cu = tid & 7, r0 = tid >> 3;
    const int tile = blockIdx.x, b = blockIdx.y;
    const int nch = tile / 16 + 1;
    const int slotBase = (b * 64 + tile) * 4;
#pragma unroll
    for (int i = 0; i < 2; ++i) {
        const int row = r0 + 32 * i;
        float L = 0.0f, acc[8];
#pragma unroll
        for (int j = 0; j < 8; ++j) acc[j] = 0.0f;
#pragma unroll
        for (int c = 0; c < 4; ++c) {
            const bool act = c < nch;
            float lraw = Ml[(size_t)(slotBase + c) * 64 + row];
            short8 ov = *(const short8*)(Op + (size_t)(slotBase + c) * 4096 + (size_t)row * 64 + cu * 8);
            L += act ? lraw : 0.0f;
#pragma unroll
            for (int j = 0; j < 8; ++j)
                acc[j] += act ? b2f((u16)ov[j]) : 0.0f;
        }
        float inv = 1.0f / L;
        float* dst = out + ((size_t)(b << 12) + tile * 64 + row) * 64 + cu * 8;
        *(float4*)(dst)     = make_float4(acc[0] * inv, acc[1] * inv, acc[2] * inv, acc[3] * inv);
        *(float4*)(dst + 4) = make_float4(acc[4] * inv, acc[5] * inv, acc[6] * inv, acc[7] * inv);
    }
}

extern "C" void kernel_launch(void* const* d_in, const int* in_sizes, int n_in,
                              void* d_out, int out_size, void* d_ws, size_t ws_size,
                              hipStream_t stream) {
    const float* x  = (const float*)d_in[0];
    const float* Wk = (const float*)d_in[1];
    const float* Wq = (const float*)d_in[2];
    const float* Wv = (const float*)d_in[3];

    u16* ws16 = (u16*)d_ws;
    u16* Wt = ws16;                          // 8 * 196608  = 1,572,864 u16 (3.1 MB)
    u16* Kb = Wt + 1572864;                  // 1,048,576          (2 MB)
    u16* Qb = Kb + 1048576;                  // 4 * 1,048,576      (8 MB, replicas)
    u16* Vt = Qb + 4194304;                  // 4 * 1,048,576      (8 MB, replicas)
    u16* Op = Vt + 4194304;                  // 4,194,304          (8.4 MB, 1024 slots)
    float* Ml = (float*)(Op + 8388608);      // 65,536 f32         (0.25 MB)
    // total ws ~38.6 MB (Op region oversized, harmless)

    wt_kernel<<<dim3(32, 3), 256, 0, stream>>>(Wk, Wq, Wv, Wt);
    proj_kernel<<<512, 256, 0, stream>>>(x, Wt, Kb, Qb, Vt);
    attn_kernel<<<dim3(160, 4), 256, 0, stream>>>(Kb, Qb, Vt, Op, Ml);
    combine_kernel<<<dim3(64, 4), 256, 0, stream>>>(Op, Ml, (float*)d_out);
}